// Round 1
// baseline (1126.378 us; speedup 1.0000x reference)
//
#include <hip/hip_runtime.h>

#define N_NODES 100000
#define N_EDGES 1600000
#define C 128

// ---------------- CSR build ----------------

__global__ void k_zero_int(int* __restrict__ p, int n) {
    int i = blockIdx.x * blockDim.x + threadIdx.x;
    if (i < n) p[i] = 0;
}

__global__ void k_count(const int* __restrict__ dst, int* __restrict__ cnt) {
    int e = blockIdx.x * blockDim.x + threadIdx.x;
    if (e < N_EDGES) atomicAdd(&cnt[dst[e]], 1);
}

// Single-workgroup exclusive scan over cnt -> rowptr; also copies the
// exclusive prefix back into cnt so k_fill can use it as the running fill
// cursor (counting sort).
__global__ __launch_bounds__(1024) void k_scan(int* __restrict__ cnt,
                                               int* __restrict__ rowptr) {
    __shared__ int s[1024];
    __shared__ int carry;
    const int tid = threadIdx.x;
    if (tid == 0) carry = 0;
    __syncthreads();
    const int CHUNK = 8;
    for (int base = 0; base < N_NODES; base += 1024 * CHUNK) {
        int v[CHUNK];
        int tot = 0;
        int i0 = base + tid * CHUNK;
#pragma unroll
        for (int m = 0; m < CHUNK; m++) {
            int i = i0 + m;
            v[m] = (i < N_NODES) ? cnt[i] : 0;
            tot += v[m];
        }
        s[tid] = tot;
        __syncthreads();
        // Hillis-Steele inclusive scan of the 1024 per-thread totals
        for (int off = 1; off < 1024; off <<= 1) {
            int t2 = (tid >= off) ? s[tid - off] : 0;
            __syncthreads();
            s[tid] += t2;
            __syncthreads();
        }
        int excl = s[tid] - tot;
        int run = carry + excl;
#pragma unroll
        for (int m = 0; m < CHUNK; m++) {
            int i = i0 + m;
            if (i < N_NODES) {
                rowptr[i] = run;
                cnt[i] = run;  // fill cursor for k_fill
            }
            run += v[m];
        }
        __syncthreads();
        if (tid == 1023) carry += s[1023];
        __syncthreads();
    }
    if (tid == 0) rowptr[N_NODES] = N_EDGES;
}

__global__ void k_fill(const int* __restrict__ src, const int* __restrict__ dst,
                       int* __restrict__ cursor, int* __restrict__ col) {
    int e = blockIdx.x * blockDim.x + threadIdx.x;
    if (e < N_EDGES) {
        int p = atomicAdd(&cursor[dst[e]], 1);
        col[p] = src[e];
    }
}

// ---------------- mean aggregation: one wave (64 lanes) per node ----------------

__global__ __launch_bounds__(256) void k_mean(const float* __restrict__ X,
                                              float* __restrict__ M,
                                              const int* __restrict__ rowptr,
                                              const int* __restrict__ col) {
    int node = blockIdx.x * 4 + (threadIdx.x >> 6);
    if (node >= N_NODES) return;
    int lane = threadIdx.x & 63;
    int beg = rowptr[node], end = rowptr[node + 1];
    float2 acc = make_float2(0.f, 0.f);
    for (int e = beg; e < end; e++) {
        int s = col[e];
        const float2* xr = reinterpret_cast<const float2*>(X + (size_t)s * C);
        float2 t = xr[lane];
        acc.x += t.x;
        acc.y += t.y;
    }
    int deg = end - beg;
    float inv = 1.0f / (float)((deg > 0) ? deg : 1);
    float2* mr = reinterpret_cast<float2*>(M + (size_t)node * C);
    mr[lane] = make_float2(acc.x * inv, acc.y * inv);
}

// ---------------- fused SAGE linear: H = relu(X @ Wl^T + M @ Wr^T + b) ----------
// 128x128 output tile, BK=16, 256 threads, 8x8 micro-tile per thread.
// LDS rows padded to 132 floats: write bank-stride becomes kk*4 -> 2-way
// conflicts only (free); 528B row stride keeps 16B alignment.

template <int RELU>
__global__ __launch_bounds__(256) void k_gemm(const float* __restrict__ X,
                                              const float* __restrict__ Mn,
                                              const float* __restrict__ Wl,
                                              const float* __restrict__ Wr,
                                              const float* __restrict__ bias,
                                              float* __restrict__ H) {
    __shared__ float Xs[16][132];
    __shared__ float Ws[16][132];
    const int tid = threadIdx.x;
    const int tx = tid & 15;   // output-channel group (8 outputs each)
    const int ty = tid >> 4;   // node group (8 nodes each)
    const int n0 = blockIdx.x * 128;

    float acc[8][8];
#pragma unroll
    for (int i = 0; i < 8; i++)
#pragma unroll
        for (int j = 0; j < 8; j++) acc[i][j] = 0.f;

#pragma unroll
    for (int phase = 0; phase < 2; ++phase) {
        const float* Xp = phase ? Mn : X;
        const float* Wp = phase ? Wr : Wl;
        for (int k0 = 0; k0 < C; k0 += 16) {
#pragma unroll
            for (int i = 0; i < 8; i++) {
                int idx = tid + i * 256;      // 0..2047
                int row = idx >> 4;           // node within tile / output j
                int kk = idx & 15;
                int n = n0 + row;
                Xs[kk][row] = (n < N_NODES) ? Xp[(size_t)n * C + k0 + kk] : 0.f;
                Ws[kk][row] = Wp[(size_t)row * C + k0 + kk];
            }
            __syncthreads();
#pragma unroll
            for (int kk = 0; kk < 16; ++kk) {
                float a[8], b[8];
#pragma unroll
                for (int i = 0; i < 8; i++) a[i] = Xs[kk][ty * 8 + i];
#pragma unroll
                for (int i = 0; i < 8; i++) b[i] = Ws[kk][tx * 8 + i];
#pragma unroll
                for (int i = 0; i < 8; i++)
#pragma unroll
                    for (int j = 0; j < 8; j++) acc[i][j] += a[i] * b[j];
            }
            __syncthreads();
        }
    }

#pragma unroll
    for (int i = 0; i < 8; i++) {
        int n = n0 + ty * 8 + i;
        if (n >= N_NODES) continue;
#pragma unroll
        for (int j = 0; j < 8; j++) {
            float v = acc[i][j] + bias[tx * 8 + j];
            if (RELU) v = fmaxf(v, 0.f);
            H[(size_t)n * C + tx * 8 + j] = v;
        }
    }
}

// ---------------- output head: out[n] = dot(Wo, H[n]) + bo ----------------

__global__ __launch_bounds__(256) void k_head(const float* __restrict__ H,
                                              const float* __restrict__ Wo,
                                              const float* __restrict__ bo,
                                              float* __restrict__ out) {
    int node = blockIdx.x * 4 + (threadIdx.x >> 6);
    if (node >= N_NODES) return;
    int lane = threadIdx.x & 63;
    const float2* hr = reinterpret_cast<const float2*>(H + (size_t)node * C);
    const float2* wr = reinterpret_cast<const float2*>(Wo);
    float2 h = hr[lane];
    float2 w = wr[lane];
    float p = h.x * w.x + h.y * w.y;
#pragma unroll
    for (int off = 32; off > 0; off >>= 1) p += __shfl_xor(p, off);
    if (lane == 0) out[node] = p + bo[0];
}

// ---------------- launch ----------------

extern "C" void kernel_launch(void* const* d_in, const int* in_sizes, int n_in,
                              void* d_out, int out_size, void* d_ws, size_t ws_size,
                              hipStream_t stream) {
    const float* x   = (const float*)d_in[0];
    const int*   ei  = (const int*)d_in[1];
    const float* Wl1 = (const float*)d_in[2];
    const float* bl1 = (const float*)d_in[3];
    const float* Wr1 = (const float*)d_in[4];
    const float* Wl2 = (const float*)d_in[5];
    const float* bl2 = (const float*)d_in[6];
    const float* Wr2 = (const float*)d_in[7];
    const float* Wo  = (const float*)d_in[8];
    const float* bo  = (const float*)d_in[9];
    float* out = (float*)d_out;

    const int* src = ei;             // edge_index[0, :]
    const int* dst = ei + N_EDGES;   // edge_index[1, :]

    // carve workspace (~110 MB total)
    char* ws = (char*)d_ws;
    auto carve = [&](size_t bytes) {
        char* p = ws;
        ws += (bytes + 1023) & ~(size_t)1023;
        return p;
    };
    int*   cnt    = (int*)carve((size_t)N_NODES * 4);
    int*   rowptr = (int*)carve((size_t)(N_NODES + 1) * 4);
    int*   col    = (int*)carve((size_t)N_EDGES * 4);
    float* M      = (float*)carve((size_t)N_NODES * C * 4);
    float* H      = (float*)carve((size_t)N_NODES * C * 4);

    // CSR build (recomputed every call; deterministic up to fp-sum order)
    k_zero_int<<<(N_NODES + 255) / 256, 256, 0, stream>>>(cnt, N_NODES);
    k_count<<<(N_EDGES + 255) / 256, 256, 0, stream>>>(dst, cnt);
    k_scan<<<1, 1024, 0, stream>>>(cnt, rowptr);
    k_fill<<<(N_EDGES + 255) / 256, 256, 0, stream>>>(src, dst, cnt, col);

    dim3 gN((N_NODES + 3) / 4), b256(256);
    dim3 gG((N_NODES + 127) / 128);

    // layer 1
    k_mean<<<gN, b256, 0, stream>>>(x, M, rowptr, col);
    k_gemm<1><<<gG, b256, 0, stream>>>(x, M, Wl1, Wr1, bl1, H);
    // layer 2 (in-place H: each block reads only its own rows before writing)
    k_mean<<<gN, b256, 0, stream>>>(H, M, rowptr, col);
    k_gemm<1><<<gG, b256, 0, stream>>>(H, M, Wl2, Wr2, bl2, H);
    // head
    k_head<<<gN, b256, 0, stream>>>(H, Wo, bo, out);
}

// Round 2
// 579.190 us; speedup vs baseline: 1.9447x; 1.9447x over previous
//
#include <hip/hip_runtime.h>
#include <hip/hip_fp16.h>

#define N_NODES 100000
#define N_EDGES 1600000
#define C 128

typedef _Float16 half8 __attribute__((ext_vector_type(8)));
typedef float f32x4 __attribute__((ext_vector_type(4)));

// ---------------- CSR build ----------------

__global__ void k_zero_int(int* __restrict__ p, int n) {
    int i = blockIdx.x * blockDim.x + threadIdx.x;
    if (i < n) p[i] = 0;
}

__global__ void k_count(const int* __restrict__ dst, int* __restrict__ cnt) {
    int e = blockIdx.x * blockDim.x + threadIdx.x;
    if (e < N_EDGES) atomicAdd(&cnt[dst[e]], 1);
}

__global__ __launch_bounds__(1024) void k_scan(int* __restrict__ cnt,
                                               int* __restrict__ rowptr) {
    __shared__ int s[1024];
    __shared__ int carry;
    const int tid = threadIdx.x;
    if (tid == 0) carry = 0;
    __syncthreads();
    const int CHUNK = 8;
    for (int base = 0; base < N_NODES; base += 1024 * CHUNK) {
        int v[CHUNK];
        int tot = 0;
        int i0 = base + tid * CHUNK;
#pragma unroll
        for (int m = 0; m < CHUNK; m++) {
            int i = i0 + m;
            v[m] = (i < N_NODES) ? cnt[i] : 0;
            tot += v[m];
        }
        s[tid] = tot;
        __syncthreads();
        for (int off = 1; off < 1024; off <<= 1) {
            int t2 = (tid >= off) ? s[tid - off] : 0;
            __syncthreads();
            s[tid] += t2;
            __syncthreads();
        }
        int excl = s[tid] - tot;
        int run = carry + excl;
#pragma unroll
        for (int m = 0; m < CHUNK; m++) {
            int i = i0 + m;
            if (i < N_NODES) {
                rowptr[i] = run;
                cnt[i] = run;
            }
            run += v[m];
        }
        __syncthreads();
        if (tid == 1023) carry += s[1023];
        __syncthreads();
    }
    if (tid == 0) rowptr[N_NODES] = N_EDGES;
}

__global__ void k_fill(const int* __restrict__ src, const int* __restrict__ dst,
                       int* __restrict__ cursor, int* __restrict__ col) {
    int e = blockIdx.x * blockDim.x + threadIdx.x;
    if (e < N_EDGES) {
        int p = atomicAdd(&cursor[dst[e]], 1);
        col[p] = src[e];
    }
}

// ---------------- fp32 -> fp16 feature convert ----------------

__global__ void k_cvt(const float* __restrict__ X, __half* __restrict__ Y, int n4) {
    int i = blockIdx.x * blockDim.x + threadIdx.x;
    if (i < n4) {
        float4 v = ((const float4*)X)[i];
        __half2 a = __floats2half2_rn(v.x, v.y);
        __half2 b = __floats2half2_rn(v.z, v.w);
        ((__half2*)Y)[i * 2] = a;
        ((__half2*)Y)[i * 2 + 1] = b;
    }
}

// pack [Wl | Wr] -> Wc[n][k], k in [0,256), fp16
__global__ void k_prepw(const float* __restrict__ Wl, const float* __restrict__ Wr,
                        __half* __restrict__ Wc) {
    int i = blockIdx.x * blockDim.x + threadIdx.x;
    if (i < 128 * 256) {
        int n_ = i >> 8, k = i & 255;
        float v = (k < 128) ? Wl[n_ * 128 + k] : Wr[n_ * 128 + (k - 128)];
        Wc[i] = __float2half_rn(v);
    }
}

// ---------------- mean aggregation (fp16 rows, fp32 accumulate) ----------------

__global__ __launch_bounds__(256) void k_mean_f16(const __half* __restrict__ X,
                                                  __half* __restrict__ M,
                                                  const int* __restrict__ rowptr,
                                                  const int* __restrict__ col) {
    int node = blockIdx.x * 4 + (threadIdx.x >> 6);
    if (node >= N_NODES) return;
    int lane = threadIdx.x & 63;
    int beg = rowptr[node], end = rowptr[node + 1];
    float ax = 0.f, ay = 0.f;
    int e = beg;
    for (; e + 3 < end; e += 4) {
        int s0 = col[e], s1 = col[e + 1], s2 = col[e + 2], s3 = col[e + 3];
        __half2 v0 = *(const __half2*)(X + (size_t)s0 * C + lane * 2);
        __half2 v1 = *(const __half2*)(X + (size_t)s1 * C + lane * 2);
        __half2 v2 = *(const __half2*)(X + (size_t)s2 * C + lane * 2);
        __half2 v3 = *(const __half2*)(X + (size_t)s3 * C + lane * 2);
        float2 f0 = __half22float2(v0), f1 = __half22float2(v1);
        float2 f2 = __half22float2(v2), f3 = __half22float2(v3);
        ax += (f0.x + f1.x) + (f2.x + f3.x);
        ay += (f0.y + f1.y) + (f2.y + f3.y);
    }
    for (; e < end; e++) {
        int s0 = col[e];
        float2 f0 = __half22float2(*(const __half2*)(X + (size_t)s0 * C + lane * 2));
        ax += f0.x;
        ay += f0.y;
    }
    int deg = end - beg;
    float inv = 1.0f / (float)((deg > 0) ? deg : 1);
    *(__half2*)(M + (size_t)node * C + lane * 2) = __floats2half2_rn(ax * inv, ay * inv);
}

// ---------------- MFMA GEMM: relu(A0@W[:, :128]^T + A1@W[:, 128:]^T + b) --------
// BM=128 nodes x BN=128 out-ch, K=256 concat. 4 waves (2x2), wave tile 64x64,
// 16x16x32 f16 MFMA, M_rep=N_rep=4. Double-buffered LDS, reg-staged (T14).
// LDS pitch 40 halves (80B): frag ds_read_b128 is 2-way bank aliasing (free).
// HEAD=1: fuse out[n] = relu_h2[n] . Wo + bo, skip writing H.

template <int HEAD>
__global__ __launch_bounds__(256) void k_gemm_f16(
    const __half* __restrict__ A0, const __half* __restrict__ A1,
    const __half* __restrict__ W, const float* __restrict__ bias,
    __half* __restrict__ Hout, const float* __restrict__ Wo,
    const float* __restrict__ bo, float* __restrict__ out) {
    __shared__ __half As[2][128][40];
    __shared__ __half Bs[2][128][40];
    __shared__ float outs[2][128];

    const int tid = threadIdx.x;
    const int n0 = blockIdx.x * 128;
    const int wid = tid >> 6, lane = tid & 63;
    const int wr = wid >> 1, wc = wid & 1;
    const int l15 = lane & 15, lk = lane >> 4;

    f32x4 acc[4][4];
#pragma unroll
    for (int m = 0; m < 4; m++)
#pragma unroll
        for (int n = 0; n < 4; n++) acc[m][n] = (f32x4)(0.0f);

    // per-thread staging map: L = tid + i*256 -> row = L>>2 (0..127), seg = L&3
    const int row0 = tid >> 2, seg0 = (tid & 3) * 8;
    const int row1 = (tid + 256) >> 2, seg1 = seg0;  // (tid+256)&3 == tid&3

    uint4 ra[2], rb[2];
    auto stage_load = [&](int t) {
        int kg = t * 32;
        const __half* Ap = (kg < 128) ? A0 : A1;
        int k0 = kg & 127;
        int n_ = n0 + row0;
        ra[0] = (n_ < N_NODES) ? *(const uint4*)(Ap + (size_t)n_ * C + k0 + seg0)
                               : make_uint4(0, 0, 0, 0);
        rb[0] = *(const uint4*)(W + row0 * 256 + kg + seg0);
        n_ = n0 + row1;
        ra[1] = (n_ < N_NODES) ? *(const uint4*)(Ap + (size_t)n_ * C + k0 + seg1)
                               : make_uint4(0, 0, 0, 0);
        rb[1] = *(const uint4*)(W + row1 * 256 + kg + seg1);
    };
    auto stage_write = [&](int b) {
        *(uint4*)&As[b][row0][seg0] = ra[0];
        *(uint4*)&Bs[b][row0][seg0] = rb[0];
        *(uint4*)&As[b][row1][seg1] = ra[1];
        *(uint4*)&Bs[b][row1][seg1] = rb[1];
    };

    stage_load(0);
    stage_write(0);
    __syncthreads();

    for (int t = 0; t < 8; t++) {
        int cur = t & 1;
        if (t < 7) stage_load(t + 1);  // issue early: latency hides under MFMA
        half8 af[4], bf[4];
#pragma unroll
        for (int m = 0; m < 4; m++)
            af[m] = *(const half8*)&As[cur][wr * 64 + m * 16 + l15][lk * 8];
#pragma unroll
        for (int n = 0; n < 4; n++)
            bf[n] = *(const half8*)&Bs[cur][wc * 64 + n * 16 + l15][lk * 8];
#pragma unroll
        for (int m = 0; m < 4; m++)
#pragma unroll
            for (int n = 0; n < 4; n++)
                acc[m][n] =
                    __builtin_amdgcn_mfma_f32_16x16x32_f16(af[m], bf[n], acc[m][n], 0, 0, 0);
        if (t < 7) stage_write(cur ^ 1);
        __syncthreads();
    }

    // epilogue: bias + relu
    float bv[4];
#pragma unroll
    for (int n = 0; n < 4; n++) bv[n] = bias[wc * 64 + n * 16 + l15];
#pragma unroll
    for (int m = 0; m < 4; m++)
#pragma unroll
        for (int n = 0; n < 4; n++)
#pragma unroll
            for (int r = 0; r < 4; r++)
                acc[m][n][r] = fmaxf(acc[m][n][r] + bv[n], 0.f);

    if (!HEAD) {
        // C/D layout: col = l15, row_local = m*16 + lk*4 + r  (within wave tile)
#pragma unroll
        for (int m = 0; m < 4; m++) {
#pragma unroll
            for (int r = 0; r < 4; r++) {
                int n_ = n0 + wr * 64 + m * 16 + lk * 4 + r;
                if (n_ < N_NODES) {
#pragma unroll
                    for (int n = 0; n < 4; n++)
                        Hout[(size_t)n_ * C + wc * 64 + n * 16 + l15] =
                            __float2half_rn(acc[m][n][r]);
                }
            }
        }
    } else {
        // fused head: out[row] = sum_col h2[row][col] * Wo[col] + bo
        float wv[4];
#pragma unroll
        for (int n = 0; n < 4; n++) wv[n] = Wo[wc * 64 + n * 16 + l15];
#pragma unroll
        for (int m = 0; m < 4; m++) {
#pragma unroll
            for (int r = 0; r < 4; r++) {
                float p = acc[m][0][r] * wv[0] + acc[m][1][r] * wv[1] +
                          acc[m][2][r] * wv[2] + acc[m][3][r] * wv[3];
                p += __shfl_xor(p, 1);
                p += __shfl_xor(p, 2);
                p += __shfl_xor(p, 4);
                p += __shfl_xor(p, 8);
                if (l15 == 0) outs[wc][wr * 64 + m * 16 + lk * 4 + r] = p;
            }
        }
        __syncthreads();
        if (tid < 128) {
            int n_ = n0 + tid;
            if (n_ < N_NODES) out[n_] = outs[0][tid] + outs[1][tid] + bo[0];
        }
    }
}

// ---------------- launch ----------------

extern "C" void kernel_launch(void* const* d_in, const int* in_sizes, int n_in,
                              void* d_out, int out_size, void* d_ws, size_t ws_size,
                              hipStream_t stream) {
    const float* x   = (const float*)d_in[0];
    const int*   ei  = (const int*)d_in[1];
    const float* Wl1 = (const float*)d_in[2];
    const float* bl1 = (const float*)d_in[3];
    const float* Wr1 = (const float*)d_in[4];
    const float* Wl2 = (const float*)d_in[5];
    const float* bl2 = (const float*)d_in[6];
    const float* Wr2 = (const float*)d_in[7];
    const float* Wo  = (const float*)d_in[8];
    const float* bo  = (const float*)d_in[9];
    float* out = (float*)d_out;

    const int* src = ei;
    const int* dst = ei + N_EDGES;

    char* ws = (char*)d_ws;
    auto carve = [&](size_t bytes) {
        char* p = ws;
        ws += (bytes + 1023) & ~(size_t)1023;
        return p;
    };
    int*    cnt    = (int*)carve((size_t)N_NODES * 4);
    int*    rowptr = (int*)carve((size_t)(N_NODES + 1) * 4);
    int*    col    = (int*)carve((size_t)N_EDGES * 4);
    __half* Xh     = (__half*)carve((size_t)N_NODES * C * 2);
    __half* Mh     = (__half*)carve((size_t)N_NODES * C * 2);
    __half* Hh     = (__half*)carve((size_t)N_NODES * C * 2);
    __half* Wc1    = (__half*)carve((size_t)128 * 256 * 2);
    __half* Wc2    = (__half*)carve((size_t)128 * 256 * 2);

    // CSR build
    k_zero_int<<<(N_NODES + 255) / 256, 256, 0, stream>>>(cnt, N_NODES);
    k_count<<<(N_EDGES + 255) / 256, 256, 0, stream>>>(dst, cnt);
    k_scan<<<1, 1024, 0, stream>>>(cnt, rowptr);
    k_fill<<<(N_EDGES + 255) / 256, 256, 0, stream>>>(src, dst, cnt, col);

    // fp16 conversions / weight packing
    int n4 = N_NODES * C / 4;
    k_cvt<<<(n4 + 255) / 256, 256, 0, stream>>>(x, Xh, n4);
    k_prepw<<<128, 256, 0, stream>>>(Wl1, Wr1, Wc1);
    k_prepw<<<128, 256, 0, stream>>>(Wl2, Wr2, Wc2);

    dim3 gN((N_NODES + 3) / 4), b256(256);
    dim3 gG((N_NODES + 127) / 128);

    // layer 1
    k_mean_f16<<<gN, b256, 0, stream>>>(Xh, Mh, rowptr, col);
    k_gemm_f16<0><<<gG, b256, 0, stream>>>(Xh, Mh, Wc1, bl1, Hh, nullptr, nullptr, nullptr);
    // layer 2 + fused head
    k_mean_f16<<<gN, b256, 0, stream>>>(Hh, Mh, rowptr, col);
    k_gemm_f16<1><<<gG, b256, 0, stream>>>(Hh, Mh, Wc2, bl2, nullptr, Wo, bo, out);
}

// Round 3
// 442.501 us; speedup vs baseline: 2.5455x; 1.3089x over previous
//
#include <hip/hip_runtime.h>
#include <hip/hip_fp16.h>

#define N_NODES 100000
#define N_EDGES 1600000
#define C 128
#define SCAN_TILE 2048
#define SCAN_BLOCKS ((N_NODES + SCAN_TILE - 1) / SCAN_TILE)  // 49

typedef _Float16 half8 __attribute__((ext_vector_type(8)));
typedef float f32x4 __attribute__((ext_vector_type(4)));

// ---------------- CSR build ----------------

__global__ void k_zero_int(int* __restrict__ p, int n) {
    int i = blockIdx.x * blockDim.x + threadIdx.x;
    if (i < n) p[i] = 0;
}

__global__ void k_count(const int* __restrict__ dst, int* __restrict__ cnt) {
    int e = blockIdx.x * blockDim.x + threadIdx.x;
    if (e < N_EDGES) atomicAdd(&cnt[dst[e]], 1);
}

// Two-level scan, stage 1: per-block (2048-elem) sums.
__global__ __launch_bounds__(256) void k_partsum(const int* __restrict__ cnt,
                                                 int* __restrict__ bsum) {
    int base = blockIdx.x * SCAN_TILE;
    int t = threadIdx.x;
    int s = 0;
#pragma unroll
    for (int m = 0; m < 8; m++) {
        int i = base + t * 8 + m;
        if (i < N_NODES) s += cnt[i];
    }
#pragma unroll
    for (int off = 32; off > 0; off >>= 1) s += __shfl_down(s, off);
    __shared__ int ws[4];
    int wid = t >> 6, lane = t & 63;
    if (lane == 0) ws[wid] = s;
    __syncthreads();
    if (t == 0) bsum[blockIdx.x] = ws[0] + ws[1] + ws[2] + ws[3];
}

// Stage 2: exclusive scan of the SCAN_BLOCKS (<=64) block sums, one wave.
__global__ void k_scan_bsums(int* __restrict__ bsum) {
    int lane = threadIdx.x;  // 64 threads
    int orig = (lane < SCAN_BLOCKS) ? bsum[lane] : 0;
    int v = orig;
#pragma unroll
    for (int off = 1; off < 64; off <<= 1) {
        int u = __shfl_up(v, off);
        if (lane >= off) v += u;
    }
    if (lane < SCAN_BLOCKS) bsum[lane] = v - orig;  // exclusive
}

// Stage 3: local scan + block offset -> rowptr, and reset cnt as fill cursor.
__global__ __launch_bounds__(256) void k_apply(int* __restrict__ cnt,
                                               const int* __restrict__ bsum,
                                               int* __restrict__ rowptr) {
    int base = blockIdx.x * SCAN_TILE;
    int t = threadIdx.x;
    int lane = t & 63, wid = t >> 6;
    int v[8], tot = 0;
#pragma unroll
    for (int m = 0; m < 8; m++) {
        int i = base + t * 8 + m;
        v[m] = (i < N_NODES) ? cnt[i] : 0;
        tot += v[m];
    }
    int inc = tot;
#pragma unroll
    for (int off = 1; off < 64; off <<= 1) {
        int u = __shfl_up(inc, off);
        if (lane >= off) inc += u;
    }
    __shared__ int wsum[4];
    if (lane == 63) wsum[wid] = inc;
    __syncthreads();
    int woff = 0;
    for (int w = 0; w < wid; w++) woff += wsum[w];
    int run = inc - tot + woff + bsum[blockIdx.x];
#pragma unroll
    for (int m = 0; m < 8; m++) {
        int i = base + t * 8 + m;
        if (i < N_NODES) {
            rowptr[i] = run;
            cnt[i] = run;  // fill cursor
        }
        run += v[m];
    }
    if (blockIdx.x == 0 && t == 0) rowptr[N_NODES] = N_EDGES;
}

__global__ void k_fill(const int* __restrict__ src, const int* __restrict__ dst,
                       int* __restrict__ cursor, int* __restrict__ col) {
    int e = blockIdx.x * blockDim.x + threadIdx.x;
    if (e < N_EDGES) {
        int p = atomicAdd(&cursor[dst[e]], 1);
        col[p] = src[e];
    }
}

// ---------------- fp32 -> fp16 feature convert ----------------

__global__ void k_cvt(const float* __restrict__ X, __half* __restrict__ Y, int n4) {
    int i = blockIdx.x * blockDim.x + threadIdx.x;
    if (i < n4) {
        float4 v = ((const float4*)X)[i];
        __half2 a = __floats2half2_rn(v.x, v.y);
        __half2 b = __floats2half2_rn(v.z, v.w);
        ((__half2*)Y)[i * 2] = a;
        ((__half2*)Y)[i * 2 + 1] = b;
    }
}

// pack [Wl | Wr] -> Wc[n][k], k in [0,256), fp16
__global__ void k_prepw(const float* __restrict__ Wl, const float* __restrict__ Wr,
                        __half* __restrict__ Wc) {
    int i = blockIdx.x * blockDim.x + threadIdx.x;
    if (i < 128 * 256) {
        int n_ = i >> 8, k = i & 255;
        float v = (k < 128) ? Wl[n_ * 128 + k] : Wr[n_ * 128 + (k - 128)];
        Wc[i] = __float2half_rn(v);
    }
}

// ---------------- mean aggregation (fp16 rows, fp32 accumulate) ----------------

__global__ __launch_bounds__(256) void k_mean_f16(const __half* __restrict__ X,
                                                  __half* __restrict__ M,
                                                  const int* __restrict__ rowptr,
                                                  const int* __restrict__ col) {
    int node = blockIdx.x * 4 + (threadIdx.x >> 6);
    if (node >= N_NODES) return;
    int lane = threadIdx.x & 63;
    int beg = rowptr[node], end = rowptr[node + 1];
    float ax = 0.f, ay = 0.f;
    int e = beg;
    for (; e + 3 < end; e += 4) {
        int s0 = col[e], s1 = col[e + 1], s2 = col[e + 2], s3 = col[e + 3];
        __half2 v0 = *(const __half2*)(X + (size_t)s0 * C + lane * 2);
        __half2 v1 = *(const __half2*)(X + (size_t)s1 * C + lane * 2);
        __half2 v2 = *(const __half2*)(X + (size_t)s2 * C + lane * 2);
        __half2 v3 = *(const __half2*)(X + (size_t)s3 * C + lane * 2);
        float2 f0 = __half22float2(v0), f1 = __half22float2(v1);
        float2 f2 = __half22float2(v2), f3 = __half22float2(v3);
        ax += (f0.x + f1.x) + (f2.x + f3.x);
        ay += (f0.y + f1.y) + (f2.y + f3.y);
    }
    for (; e < end; e++) {
        int s0 = col[e];
        float2 f0 = __half22float2(*(const __half2*)(X + (size_t)s0 * C + lane * 2));
        ax += f0.x;
        ay += f0.y;
    }
    int deg = end - beg;
    float inv = 1.0f / (float)((deg > 0) ? deg : 1);
    *(__half2*)(M + (size_t)node * C + lane * 2) = __floats2half2_rn(ax * inv, ay * inv);
}

// ---------------- MFMA GEMM: relu(A0@W[:, :128]^T + A1@W[:, 128:]^T + b) --------

template <int HEAD>
__global__ __launch_bounds__(256) void k_gemm_f16(
    const __half* __restrict__ A0, const __half* __restrict__ A1,
    const __half* __restrict__ W, const float* __restrict__ bias,
    __half* __restrict__ Hout, const float* __restrict__ Wo,
    const float* __restrict__ bo, float* __restrict__ out) {
    __shared__ __half As[2][128][40];
    __shared__ __half Bs[2][128][40];
    __shared__ float outs[2][128];

    const int tid = threadIdx.x;
    const int n0 = blockIdx.x * 128;
    const int wid = tid >> 6, lane = tid & 63;
    const int wr = wid >> 1, wc = wid & 1;
    const int l15 = lane & 15, lk = lane >> 4;

    f32x4 acc[4][4];
#pragma unroll
    for (int m = 0; m < 4; m++)
#pragma unroll
        for (int n = 0; n < 4; n++) acc[m][n] = (f32x4)(0.0f);

    const int row0 = tid >> 2, seg0 = (tid & 3) * 8;
    const int row1 = (tid + 256) >> 2, seg1 = seg0;

    uint4 ra[2], rb[2];
    auto stage_load = [&](int t) {
        int kg = t * 32;
        const __half* Ap = (kg < 128) ? A0 : A1;
        int k0 = kg & 127;
        int n_ = n0 + row0;
        ra[0] = (n_ < N_NODES) ? *(const uint4*)(Ap + (size_t)n_ * C + k0 + seg0)
                               : make_uint4(0, 0, 0, 0);
        rb[0] = *(const uint4*)(W + row0 * 256 + kg + seg0);
        n_ = n0 + row1;
        ra[1] = (n_ < N_NODES) ? *(const uint4*)(Ap + (size_t)n_ * C + k0 + seg1)
                               : make_uint4(0, 0, 0, 0);
        rb[1] = *(const uint4*)(W + row1 * 256 + kg + seg1);
    };
    auto stage_write = [&](int b) {
        *(uint4*)&As[b][row0][seg0] = ra[0];
        *(uint4*)&Bs[b][row0][seg0] = rb[0];
        *(uint4*)&As[b][row1][seg1] = ra[1];
        *(uint4*)&Bs[b][row1][seg1] = rb[1];
    };

    stage_load(0);
    stage_write(0);
    __syncthreads();

    for (int t = 0; t < 8; t++) {
        int cur = t & 1;
        if (t < 7) stage_load(t + 1);
        half8 af[4], bf[4];
#pragma unroll
        for (int m = 0; m < 4; m++)
            af[m] = *(const half8*)&As[cur][wr * 64 + m * 16 + l15][lk * 8];
#pragma unroll
        for (int n = 0; n < 4; n++)
            bf[n] = *(const half8*)&Bs[cur][wc * 64 + n * 16 + l15][lk * 8];
#pragma unroll
        for (int m = 0; m < 4; m++)
#pragma unroll
            for (int n = 0; n < 4; n++)
                acc[m][n] =
                    __builtin_amdgcn_mfma_f32_16x16x32_f16(af[m], bf[n], acc[m][n], 0, 0, 0);
        if (t < 7) stage_write(cur ^ 1);
        __syncthreads();
    }

    float bv[4];
#pragma unroll
    for (int n = 0; n < 4; n++) bv[n] = bias[wc * 64 + n * 16 + l15];
#pragma unroll
    for (int m = 0; m < 4; m++)
#pragma unroll
        for (int n = 0; n < 4; n++)
#pragma unroll
            for (int r = 0; r < 4; r++)
                acc[m][n][r] = fmaxf(acc[m][n][r] + bv[n], 0.f);

    if (!HEAD) {
#pragma unroll
        for (int m = 0; m < 4; m++) {
#pragma unroll
            for (int r = 0; r < 4; r++) {
                int n_ = n0 + wr * 64 + m * 16 + lk * 4 + r;
                if (n_ < N_NODES) {
#pragma unroll
                    for (int n = 0; n < 4; n++)
                        Hout[(size_t)n_ * C + wc * 64 + n * 16 + l15] =
                            __float2half_rn(acc[m][n][r]);
                }
            }
        }
    } else {
        float wv[4];
#pragma unroll
        for (int n = 0; n < 4; n++) wv[n] = Wo[wc * 64 + n * 16 + l15];
#pragma unroll
        for (int m = 0; m < 4; m++) {
#pragma unroll
            for (int r = 0; r < 4; r++) {
                float p = acc[m][0][r] * wv[0] + acc[m][1][r] * wv[1] +
                          acc[m][2][r] * wv[2] + acc[m][3][r] * wv[3];
                p += __shfl_xor(p, 1);
                p += __shfl_xor(p, 2);
                p += __shfl_xor(p, 4);
                p += __shfl_xor(p, 8);
                if (l15 == 0) outs[wc][wr * 64 + m * 16 + lk * 4 + r] = p;
            }
        }
        __syncthreads();
        if (tid < 128) {
            int n_ = n0 + tid;
            if (n_ < N_NODES) out[n_] = outs[0][tid] + outs[1][tid] + bo[0];
        }
    }
}

// ---------------- launch ----------------

extern "C" void kernel_launch(void* const* d_in, const int* in_sizes, int n_in,
                              void* d_out, int out_size, void* d_ws, size_t ws_size,
                              hipStream_t stream) {
    const float* x   = (const float*)d_in[0];
    const int*   ei  = (const int*)d_in[1];
    const float* Wl1 = (const float*)d_in[2];
    const float* bl1 = (const float*)d_in[3];
    const float* Wr1 = (const float*)d_in[4];
    const float* Wl2 = (const float*)d_in[5];
    const float* bl2 = (const float*)d_in[6];
    const float* Wr2 = (const float*)d_in[7];
    const float* Wo  = (const float*)d_in[8];
    const float* bo  = (const float*)d_in[9];
    float* out = (float*)d_out;

    const int* src = ei;
    const int* dst = ei + N_EDGES;

    char* ws = (char*)d_ws;
    auto carve = [&](size_t bytes) {
        char* p = ws;
        ws += (bytes + 1023) & ~(size_t)1023;
        return p;
    };
    int*    cnt    = (int*)carve((size_t)N_NODES * 4);
    int*    rowptr = (int*)carve((size_t)(N_NODES + 1) * 4);
    int*    col    = (int*)carve((size_t)N_EDGES * 4);
    int*    bsum   = (int*)carve((size_t)SCAN_BLOCKS * 4);
    __half* Xh     = (__half*)carve((size_t)N_NODES * C * 2);
    __half* Mh     = (__half*)carve((size_t)N_NODES * C * 2);
    __half* Hh     = (__half*)carve((size_t)N_NODES * C * 2);
    __half* Wc1    = (__half*)carve((size_t)128 * 256 * 2);
    __half* Wc2    = (__half*)carve((size_t)128 * 256 * 2);

    // CSR build (two-level scan)
    k_zero_int<<<(N_NODES + 255) / 256, 256, 0, stream>>>(cnt, N_NODES);
    k_count<<<(N_EDGES + 255) / 256, 256, 0, stream>>>(dst, cnt);
    k_partsum<<<SCAN_BLOCKS, 256, 0, stream>>>(cnt, bsum);
    k_scan_bsums<<<1, 64, 0, stream>>>(bsum);
    k_apply<<<SCAN_BLOCKS, 256, 0, stream>>>(cnt, bsum, rowptr);
    k_fill<<<(N_EDGES + 255) / 256, 256, 0, stream>>>(src, dst, cnt, col);

    // fp16 conversions / weight packing
    int n4 = N_NODES * C / 4;
    k_cvt<<<(n4 + 255) / 256, 256, 0, stream>>>(x, Xh, n4);
    k_prepw<<<128, 256, 0, stream>>>(Wl1, Wr1, Wc1);
    k_prepw<<<128, 256, 0, stream>>>(Wl2, Wr2, Wc2);

    dim3 gN((N_NODES + 3) / 4), b256(256);
    dim3 gG((N_NODES + 127) / 128);

    // layer 1
    k_mean_f16<<<gN, b256, 0, stream>>>(Xh, Mh, rowptr, col);
    k_gemm_f16<0><<<gG, b256, 0, stream>>>(Xh, Mh, Wc1, bl1, Hh, nullptr, nullptr, nullptr);
    // layer 2 + fused head
    k_mean_f16<<<gN, b256, 0, stream>>>(Hh, Mh, rowptr, col);
    k_gemm_f16<1><<<gG, b256, 0, stream>>>(Hh, Mh, Wc2, bl2, nullptr, Wo, bo, out);
}

// Round 4
// 301.286 us; speedup vs baseline: 3.7386x; 1.4687x over previous
//
#include <hip/hip_runtime.h>
#include <hip/hip_fp16.h>

#define N_NODES 100000
#define N_EDGES 1600000
#define C 128

// binned CSR build
#define NB_SHIFT 10
#define NB (1 << NB_SHIFT)                        // 1024 nodes per bucket
#define NBKT ((N_NODES + NB - 1) >> NB_SHIFT)     // 98 buckets
#define CPT 4096                                  // edges per stage block
#define STG_THREADS 512
#define STG_BLOCKS ((N_EDGES + CPT - 1) / CPT)    // 391

typedef _Float16 half8 __attribute__((ext_vector_type(8)));
typedef float f32x4 __attribute__((ext_vector_type(4)));

__global__ void k_zero_int(int* __restrict__ p, int n) {
    int i = blockIdx.x * blockDim.x + threadIdx.x;
    if (i < n) p[i] = 0;
}

// ---- pass A: per-bucket edge counts (LDS-aggregated) ----
__global__ __launch_bounds__(512) void k_bcount(const int* __restrict__ dst,
                                                int* __restrict__ gb) {
    __shared__ int hist[128];
    int t = threadIdx.x;
    int base = blockIdx.x * CPT;
    if (t < 128) hist[t] = 0;
    __syncthreads();
#pragma unroll
    for (int i = 0; i < 8; i++) {
        int e = base + i * STG_THREADS + t;
        if (e < N_EDGES) atomicAdd(&hist[dst[e] >> NB_SHIFT], 1);
    }
    __syncthreads();
    if (t < NBKT) {
        int h = hist[t];
        if (h) atomicAdd(&gb[t], h);
    }
}

// ---- pass B: scan bucket counts -> gbase (and init gcur) ----
__global__ __launch_bounds__(128) void k_bscan(const int* __restrict__ gb,
                                               int* __restrict__ gbase,
                                               int* __restrict__ gcur,
                                               int* __restrict__ rowptr) {
    __shared__ int sc[128];
    int t = threadIdx.x;
    int v = (t < NBKT) ? gb[t] : 0;
    sc[t] = v;
    __syncthreads();
    for (int off = 1; off < 128; off <<= 1) {
        int u = (t >= off) ? sc[t - off] : 0;
        __syncthreads();
        sc[t] += u;
        __syncthreads();
    }
    if (t < NBKT) {
        int e = sc[t] - v;  // exclusive
        gbase[t] = e;
        gcur[t] = e;
    }
    if (t == 0) {
        gbase[NBKT] = N_EDGES;
        rowptr[N_NODES] = N_EDGES;
    }
}

// ---- pass C: binned stage -> S[(src,dst)] grouped by bucket ----
__global__ __launch_bounds__(512) void k_bstage(const int* __restrict__ src,
                                                const int* __restrict__ dst,
                                                int* __restrict__ gcur,
                                                uint2* __restrict__ S) {
    __shared__ int hist[128], sc[128], lstart[128], gbaseL[128];
    __shared__ uint2 stg[CPT];
    int t = threadIdx.x;
    int base = blockIdx.x * CPT;
    int cnt = N_EDGES - base;
    if (cnt > CPT) cnt = CPT;
    if (t < 128) hist[t] = 0;
    __syncthreads();
    unsigned s_[8], d_[8];
    int r_[8], b_[8];
#pragma unroll
    for (int i = 0; i < 8; i++) {
        int li = i * STG_THREADS + t;
        if (li < cnt) {
            int e = base + li;
            s_[i] = src[e];
            d_[i] = dst[e];
            b_[i] = d_[i] >> NB_SHIFT;
            r_[i] = atomicAdd(&hist[b_[i]], 1);
        } else {
            r_[i] = -1;
        }
    }
    __syncthreads();
    int hv = (t < 128) ? hist[t] : 0;
    if (t < 128) sc[t] = hv;
    __syncthreads();
    for (int off = 1; off < 128; off <<= 1) {
        int u = (t < 128 && t >= off) ? sc[t - off] : 0;
        __syncthreads();
        if (t < 128) sc[t] += u;
        __syncthreads();
    }
    if (t < 128) lstart[t] = sc[t] - hv;
    if (t < NBKT) gbaseL[t] = hv ? atomicAdd(&gcur[t], hv) : 0;
    __syncthreads();
#pragma unroll
    for (int i = 0; i < 8; i++)
        if (r_[i] >= 0) stg[lstart[b_[i]] + r_[i]] = make_uint2(s_[i], d_[i]);
    __syncthreads();
    for (int slot = t; slot < cnt; slot += STG_THREADS) {
        uint2 ed = stg[slot];
        int b = ed.y >> NB_SHIFT;
        S[gbaseL[b] + (slot - lstart[b])] = ed;
    }
}

// ---- pass D: per-bucket fine counting sort -> rowptr + col ----
__global__ __launch_bounds__(1024) void k_bfine(const uint2* __restrict__ S,
                                                const int* __restrict__ gbase,
                                                int* __restrict__ rowptr,
                                                int* __restrict__ col) {
    __shared__ int hist[NB];
    __shared__ int wsum[16];
    int t = threadIdx.x, b = blockIdx.x;
    int nbeg = b << NB_SHIFT;
    int ebeg = gbase[b], eend = gbase[b + 1];
    hist[t] = 0;
    __syncthreads();
    for (int e = ebeg + t; e < eend; e += 1024) atomicAdd(&hist[S[e].y - nbeg], 1);
    __syncthreads();
    int v = hist[t];
    int inc = v;
    int lane = t & 63, wid = t >> 6;
#pragma unroll
    for (int off = 1; off < 64; off <<= 1) {
        int u = __shfl_up(inc, off);
        if (lane >= off) inc += u;
    }
    if (lane == 63) wsum[wid] = inc;
    __syncthreads();
    if (t < 16) {
        int w = wsum[t];
        int wi = w;
#pragma unroll
        for (int off = 1; off < 16; off <<= 1) {
            int u = __shfl_up(wi, off);
            if (t >= off) wi += u;
        }
        wsum[t] = wi;  // inclusive wave sums
    }
    __syncthreads();
    int woff = (wid == 0) ? 0 : wsum[wid - 1];
    int excl = inc - v + woff;
    int g = nbeg + t;
    if (g < N_NODES) rowptr[g] = ebeg + excl;
    __syncthreads();
    hist[t] = excl;  // becomes fill cursor (local offset within bucket)
    __syncthreads();
    for (int e = ebeg + t; e < eend; e += 1024) {
        uint2 ed = S[e];
        int p = atomicAdd(&hist[ed.y - nbeg], 1);
        col[ebeg + p] = ed.x;
    }
}

// ---------------- fp32 -> fp16 feature convert ----------------

__global__ void k_cvt(const float* __restrict__ X, __half* __restrict__ Y, int n4) {
    int i = blockIdx.x * blockDim.x + threadIdx.x;
    if (i < n4) {
        float4 v = ((const float4*)X)[i];
        __half2 a = __floats2half2_rn(v.x, v.y);
        __half2 b = __floats2half2_rn(v.z, v.w);
        ((__half2*)Y)[i * 2] = a;
        ((__half2*)Y)[i * 2 + 1] = b;
    }
}

__global__ void k_prepw(const float* __restrict__ Wl, const float* __restrict__ Wr,
                        __half* __restrict__ Wc) {
    int i = blockIdx.x * blockDim.x + threadIdx.x;
    if (i < 128 * 256) {
        int n_ = i >> 8, k = i & 255;
        float v = (k < 128) ? Wl[n_ * 128 + k] : Wr[n_ * 128 + (k - 128)];
        Wc[i] = __float2half_rn(v);
    }
}

// ---------------- mean aggregation (fp16 rows, fp32 accumulate) ----------------

__global__ __launch_bounds__(256) void k_mean_f16(const __half* __restrict__ X,
                                                  __half* __restrict__ M,
                                                  const int* __restrict__ rowptr,
                                                  const int* __restrict__ col) {
    int node = blockIdx.x * 4 + (threadIdx.x >> 6);
    if (node >= N_NODES) return;
    int lane = threadIdx.x & 63;
    int beg = rowptr[node], end = rowptr[node + 1];
    float ax = 0.f, ay = 0.f;
    int e = beg;
    for (; e + 3 < end; e += 4) {
        int s0 = col[e], s1 = col[e + 1], s2 = col[e + 2], s3 = col[e + 3];
        __half2 v0 = *(const __half2*)(X + (size_t)s0 * C + lane * 2);
        __half2 v1 = *(const __half2*)(X + (size_t)s1 * C + lane * 2);
        __half2 v2 = *(const __half2*)(X + (size_t)s2 * C + lane * 2);
        __half2 v3 = *(const __half2*)(X + (size_t)s3 * C + lane * 2);
        float2 f0 = __half22float2(v0), f1 = __half22float2(v1);
        float2 f2 = __half22float2(v2), f3 = __half22float2(v3);
        ax += (f0.x + f1.x) + (f2.x + f3.x);
        ay += (f0.y + f1.y) + (f2.y + f3.y);
    }
    for (; e < end; e++) {
        int s0 = col[e];
        float2 f0 = __half22float2(*(const __half2*)(X + (size_t)s0 * C + lane * 2));
        ax += f0.x;
        ay += f0.y;
    }
    int deg = end - beg;
    float inv = 1.0f / (float)((deg > 0) ? deg : 1);
    *(__half2*)(M + (size_t)node * C + lane * 2) = __floats2half2_rn(ax * inv, ay * inv);
}

// ---------------- MFMA GEMM: relu(A0@W[:, :128]^T + A1@W[:, 128:]^T + b) --------

template <int HEAD>
__global__ __launch_bounds__(256) void k_gemm_f16(
    const __half* __restrict__ A0, const __half* __restrict__ A1,
    const __half* __restrict__ W, const float* __restrict__ bias,
    __half* __restrict__ Hout, const float* __restrict__ Wo,
    const float* __restrict__ bo, float* __restrict__ out) {
    __shared__ __half As[2][128][40];
    __shared__ __half Bs[2][128][40];
    __shared__ float outs[2][128];

    const int tid = threadIdx.x;
    const int n0 = blockIdx.x * 128;
    const int wid = tid >> 6, lane = tid & 63;
    const int wr = wid >> 1, wc = wid & 1;
    const int l15 = lane & 15, lk = lane >> 4;

    f32x4 acc[4][4];
#pragma unroll
    for (int m = 0; m < 4; m++)
#pragma unroll
        for (int n = 0; n < 4; n++) acc[m][n] = (f32x4)(0.0f);

    const int row0 = tid >> 2, seg0 = (tid & 3) * 8;
    const int row1 = (tid + 256) >> 2, seg1 = seg0;

    uint4 ra[2], rb[2];
    auto stage_load = [&](int t) {
        int kg = t * 32;
        const __half* Ap = (kg < 128) ? A0 : A1;
        int k0 = kg & 127;
        int n_ = n0 + row0;
        ra[0] = (n_ < N_NODES) ? *(const uint4*)(Ap + (size_t)n_ * C + k0 + seg0)
                               : make_uint4(0, 0, 0, 0);
        rb[0] = *(const uint4*)(W + row0 * 256 + kg + seg0);
        n_ = n0 + row1;
        ra[1] = (n_ < N_NODES) ? *(const uint4*)(Ap + (size_t)n_ * C + k0 + seg1)
                               : make_uint4(0, 0, 0, 0);
        rb[1] = *(const uint4*)(W + row1 * 256 + kg + seg1);
    };
    auto stage_write = [&](int b) {
        *(uint4*)&As[b][row0][seg0] = ra[0];
        *(uint4*)&Bs[b][row0][seg0] = rb[0];
        *(uint4*)&As[b][row1][seg1] = ra[1];
        *(uint4*)&Bs[b][row1][seg1] = rb[1];
    };

    stage_load(0);
    stage_write(0);
    __syncthreads();

    for (int t = 0; t < 8; t++) {
        int cur = t & 1;
        if (t < 7) stage_load(t + 1);
        half8 af[4], bf[4];
#pragma unroll
        for (int m = 0; m < 4; m++)
            af[m] = *(const half8*)&As[cur][wr * 64 + m * 16 + l15][lk * 8];
#pragma unroll
        for (int n = 0; n < 4; n++)
            bf[n] = *(const half8*)&Bs[cur][wc * 64 + n * 16 + l15][lk * 8];
#pragma unroll
        for (int m = 0; m < 4; m++)
#pragma unroll
            for (int n = 0; n < 4; n++)
                acc[m][n] =
                    __builtin_amdgcn_mfma_f32_16x16x32_f16(af[m], bf[n], acc[m][n], 0, 0, 0);
        if (t < 7) stage_write(cur ^ 1);
        __syncthreads();
    }

    float bv[4];
#pragma unroll
    for (int n = 0; n < 4; n++) bv[n] = bias[wc * 64 + n * 16 + l15];
#pragma unroll
    for (int m = 0; m < 4; m++)
#pragma unroll
        for (int n = 0; n < 4; n++)
#pragma unroll
            for (int r = 0; r < 4; r++)
                acc[m][n][r] = fmaxf(acc[m][n][r] + bv[n], 0.f);

    if (!HEAD) {
#pragma unroll
        for (int m = 0; m < 4; m++) {
#pragma unroll
            for (int r = 0; r < 4; r++) {
                int n_ = n0 + wr * 64 + m * 16 + lk * 4 + r;
                if (n_ < N_NODES) {
#pragma unroll
                    for (int n = 0; n < 4; n++)
                        Hout[(size_t)n_ * C + wc * 64 + n * 16 + l15] =
                            __float2half_rn(acc[m][n][r]);
                }
            }
        }
    } else {
        float wv[4];
#pragma unroll
        for (int n = 0; n < 4; n++) wv[n] = Wo[wc * 64 + n * 16 + l15];
#pragma unroll
        for (int m = 0; m < 4; m++) {
#pragma unroll
            for (int r = 0; r < 4; r++) {
                float p = acc[m][0][r] * wv[0] + acc[m][1][r] * wv[1] +
                          acc[m][2][r] * wv[2] + acc[m][3][r] * wv[3];
                p += __shfl_xor(p, 1);
                p += __shfl_xor(p, 2);
                p += __shfl_xor(p, 4);
                p += __shfl_xor(p, 8);
                if (l15 == 0) outs[wc][wr * 64 + m * 16 + lk * 4 + r] = p;
            }
        }
        __syncthreads();
        if (tid < 128) {
            int n_ = n0 + tid;
            if (n_ < N_NODES) out[n_] = outs[0][tid] + outs[1][tid] + bo[0];
        }
    }
}

// ---------------- launch ----------------

extern "C" void kernel_launch(void* const* d_in, const int* in_sizes, int n_in,
                              void* d_out, int out_size, void* d_ws, size_t ws_size,
                              hipStream_t stream) {
    const float* x   = (const float*)d_in[0];
    const int*   ei  = (const int*)d_in[1];
    const float* Wl1 = (const float*)d_in[2];
    const float* bl1 = (const float*)d_in[3];
    const float* Wr1 = (const float*)d_in[4];
    const float* Wl2 = (const float*)d_in[5];
    const float* bl2 = (const float*)d_in[6];
    const float* Wr2 = (const float*)d_in[7];
    const float* Wo  = (const float*)d_in[8];
    const float* bo  = (const float*)d_in[9];
    float* out = (float*)d_out;

    const int* src = ei;
    const int* dst = ei + N_EDGES;

    char* ws = (char*)d_ws;
    auto carve = [&](size_t bytes) {
        char* p = ws;
        ws += (bytes + 1023) & ~(size_t)1023;
        return p;
    };
    int*    gb     = (int*)carve((size_t)NBKT * 4);
    int*    gbase  = (int*)carve((size_t)(NBKT + 1) * 4);
    int*    gcur   = (int*)carve((size_t)NBKT * 4);
    int*    rowptr = (int*)carve((size_t)(N_NODES + 1) * 4);
    int*    col    = (int*)carve((size_t)N_EDGES * 4);
    uint2*  S      = (uint2*)carve((size_t)N_EDGES * 8);
    __half* Xh     = (__half*)carve((size_t)N_NODES * C * 2);
    __half* Mh     = (__half*)carve((size_t)N_NODES * C * 2);
    __half* Hh     = (__half*)carve((size_t)N_NODES * C * 2);
    __half* Wc1    = (__half*)carve((size_t)128 * 256 * 2);
    __half* Wc2    = (__half*)carve((size_t)128 * 256 * 2);

    // binned CSR build
    k_zero_int<<<1, 256, 0, stream>>>(gb, NBKT);
    k_bcount<<<STG_BLOCKS, STG_THREADS, 0, stream>>>(dst, gb);
    k_bscan<<<1, 128, 0, stream>>>(gb, gbase, gcur, rowptr);
    k_bstage<<<STG_BLOCKS, STG_THREADS, 0, stream>>>(src, dst, gcur, S);
    k_bfine<<<NBKT, 1024, 0, stream>>>(S, gbase, rowptr, col);

    // fp16 conversions / weight packing
    int n4 = N_NODES * C / 4;
    k_cvt<<<(n4 + 255) / 256, 256, 0, stream>>>(x, Xh, n4);
    k_prepw<<<128, 256, 0, stream>>>(Wl1, Wr1, Wc1);
    k_prepw<<<128, 256, 0, stream>>>(Wl2, Wr2, Wc2);

    dim3 gN((N_NODES + 3) / 4), b256(256);
    dim3 gG((N_NODES + 127) / 128);

    // layer 1
    k_mean_f16<<<gN, b256, 0, stream>>>(Xh, Mh, rowptr, col);
    k_gemm_f16<0><<<gG, b256, 0, stream>>>(Xh, Mh, Wc1, bl1, Hh, nullptr, nullptr, nullptr);
    // layer 2 + fused head
    k_mean_f16<<<gN, b256, 0, stream>>>(Hh, Mh, rowptr, col);
    k_gemm_f16<1><<<gG, b256, 0, stream>>>(Hh, Mh, Wc2, bl2, nullptr, Wo, bo, out);
}

// Round 5
// 267.434 us; speedup vs baseline: 4.2118x; 1.1266x over previous
//
#include <hip/hip_runtime.h>
#include <hip/hip_fp16.h>

#define N_NODES 100000
#define N_EDGES 1600000
#define C 128

// binned CSR build
#define NB_SHIFT 10
#define NB (1 << NB_SHIFT)                        // 1024 nodes per bucket
#define NBKT ((N_NODES + NB - 1) >> NB_SHIFT)     // 98 buckets
#define CPT 4096                                  // edges per stage block
#define STG_THREADS 512
#define STG_BLOCKS ((N_EDGES + CPT - 1) / CPT)    // 391

typedef _Float16 half8 __attribute__((ext_vector_type(8)));
typedef float f32x4 __attribute__((ext_vector_type(4)));

__global__ void k_zero_int(int* __restrict__ p, int n) {
    int i = blockIdx.x * blockDim.x + threadIdx.x;
    if (i < n) p[i] = 0;
}

// ---- pass A: per-bucket edge counts (LDS-aggregated) ----
__global__ __launch_bounds__(512) void k_bcount(const int* __restrict__ dst,
                                                int* __restrict__ gb) {
    __shared__ int hist[128];
    int t = threadIdx.x;
    int base = blockIdx.x * CPT;
    if (t < 128) hist[t] = 0;
    __syncthreads();
#pragma unroll
    for (int i = 0; i < 8; i++) {
        int e = base + i * STG_THREADS + t;
        if (e < N_EDGES) atomicAdd(&hist[dst[e] >> NB_SHIFT], 1);
    }
    __syncthreads();
    if (t < NBKT) {
        int h = hist[t];
        if (h) atomicAdd(&gb[t], h);
    }
}

// ---- pass B: scan bucket counts -> gbase (and init gcur) ----
__global__ __launch_bounds__(128) void k_bscan(const int* __restrict__ gb,
                                               int* __restrict__ gbase,
                                               int* __restrict__ gcur,
                                               int* __restrict__ rowptr) {
    __shared__ int sc[128];
    int t = threadIdx.x;
    int v = (t < NBKT) ? gb[t] : 0;
    sc[t] = v;
    __syncthreads();
    for (int off = 1; off < 128; off <<= 1) {
        int u = (t >= off) ? sc[t - off] : 0;
        __syncthreads();
        sc[t] += u;
        __syncthreads();
    }
    if (t < NBKT) {
        int e = sc[t] - v;  // exclusive
        gbase[t] = e;
        gcur[t] = e;
    }
    if (t == 0) {
        gbase[NBKT] = N_EDGES;
        rowptr[N_NODES] = N_EDGES;
    }
}

// ---- pass C: binned stage -> S[(src,dst)] grouped by bucket ----
__global__ __launch_bounds__(512) void k_bstage(const int* __restrict__ src,
                                                const int* __restrict__ dst,
                                                int* __restrict__ gcur,
                                                uint2* __restrict__ S) {
    __shared__ int hist[128], sc[128], lstart[128], gbaseL[128];
    __shared__ uint2 stg[CPT];
    int t = threadIdx.x;
    int base = blockIdx.x * CPT;
    int cnt = N_EDGES - base;
    if (cnt > CPT) cnt = CPT;
    if (t < 128) hist[t] = 0;
    __syncthreads();
    unsigned s_[8], d_[8];
    int r_[8], b_[8];
#pragma unroll
    for (int i = 0; i < 8; i++) {
        int li = i * STG_THREADS + t;
        if (li < cnt) {
            int e = base + li;
            s_[i] = src[e];
            d_[i] = dst[e];
            b_[i] = d_[i] >> NB_SHIFT;
            r_[i] = atomicAdd(&hist[b_[i]], 1);
        } else {
            r_[i] = -1;
        }
    }
    __syncthreads();
    int hv = (t < 128) ? hist[t] : 0;
    if (t < 128) sc[t] = hv;
    __syncthreads();
    for (int off = 1; off < 128; off <<= 1) {
        int u = (t < 128 && t >= off) ? sc[t - off] : 0;
        __syncthreads();
        if (t < 128) sc[t] += u;
        __syncthreads();
    }
    if (t < 128) lstart[t] = sc[t] - hv;
    if (t < NBKT) gbaseL[t] = hv ? atomicAdd(&gcur[t], hv) : 0;
    __syncthreads();
#pragma unroll
    for (int i = 0; i < 8; i++)
        if (r_[i] >= 0) stg[lstart[b_[i]] + r_[i]] = make_uint2(s_[i], d_[i]);
    __syncthreads();
    for (int slot = t; slot < cnt; slot += STG_THREADS) {
        uint2 ed = stg[slot];
        int b = ed.y >> NB_SHIFT;
        S[gbaseL[b] + (slot - lstart[b])] = ed;
    }
}

// ---- pass D: per-bucket fine counting sort -> rowptr + col ----
__global__ __launch_bounds__(1024) void k_bfine(const uint2* __restrict__ S,
                                                const int* __restrict__ gbase,
                                                int* __restrict__ rowptr,
                                                int* __restrict__ col) {
    __shared__ int hist[NB];
    __shared__ int wsum[16];
    int t = threadIdx.x, b = blockIdx.x;
    int nbeg = b << NB_SHIFT;
    int ebeg = gbase[b], eend = gbase[b + 1];
    hist[t] = 0;
    __syncthreads();
    for (int e = ebeg + t; e < eend; e += 1024) atomicAdd(&hist[S[e].y - nbeg], 1);
    __syncthreads();
    int v = hist[t];
    int inc = v;
    int lane = t & 63, wid = t >> 6;
#pragma unroll
    for (int off = 1; off < 64; off <<= 1) {
        int u = __shfl_up(inc, off);
        if (lane >= off) inc += u;
    }
    if (lane == 63) wsum[wid] = inc;
    __syncthreads();
    if (t < 16) {
        int w = wsum[t];
        int wi = w;
#pragma unroll
        for (int off = 1; off < 16; off <<= 1) {
            int u = __shfl_up(wi, off);
            if (t >= off) wi += u;
        }
        wsum[t] = wi;  // inclusive wave sums
    }
    __syncthreads();
    int woff = (wid == 0) ? 0 : wsum[wid - 1];
    int excl = inc - v + woff;
    int g = nbeg + t;
    if (g < N_NODES) rowptr[g] = ebeg + excl;
    __syncthreads();
    hist[t] = excl;  // becomes fill cursor (local offset within bucket)
    __syncthreads();
    for (int e = ebeg + t; e < eend; e += 1024) {
        uint2 ed = S[e];
        int p = atomicAdd(&hist[ed.y - nbeg], 1);
        col[ebeg + p] = ed.x;
    }
}

// ---------------- fp32 -> fp16 feature convert ----------------

__global__ void k_cvt(const float* __restrict__ X, __half* __restrict__ Y, int n4) {
    int i = blockIdx.x * blockDim.x + threadIdx.x;
    if (i < n4) {
        float4 v = ((const float4*)X)[i];
        __half2 a = __floats2half2_rn(v.x, v.y);
        __half2 b = __floats2half2_rn(v.z, v.w);
        ((__half2*)Y)[i * 2] = a;
        ((__half2*)Y)[i * 2 + 1] = b;
    }
}

__global__ void k_prepw(const float* __restrict__ Wl, const float* __restrict__ Wr,
                        __half* __restrict__ Wc) {
    int i = blockIdx.x * blockDim.x + threadIdx.x;
    if (i < 128 * 256) {
        int n_ = i >> 8, k = i & 255;
        float v = (k < 128) ? Wl[n_ * 128 + k] : Wr[n_ * 128 + (k - 128)];
        Wc[i] = __float2half_rn(v);
    }
}

// ---------------- mean aggregation: wave/node, 4 edges in flight ----------------
// Row = 256B = 16 lanes x uint4. Lane group g=lane>>4 handles edge slot g;
// 16 edges per unrolled iteration -> 4KB outstanding per wave (4x the old MLP).
// Cross-group reduce via shfl_xor(16|32) at the end.

__global__ __launch_bounds__(256) void k_mean_f16(const __half* __restrict__ X,
                                                  __half* __restrict__ M,
                                                  const int* __restrict__ rowptr,
                                                  const int* __restrict__ col) {
    int node = blockIdx.x * 4 + (threadIdx.x >> 6);
    if (node >= N_NODES) return;
    int lane = threadIdx.x & 63;
    int g = lane >> 4;       // edge slot (0..3)
    int seg = lane & 15;     // 16B segment within 256B row
    int beg = rowptr[node], end = rowptr[node + 1];
    float acc[8];
#pragma unroll
    for (int i = 0; i < 8; i++) acc[i] = 0.f;
    for (int e0 = beg; e0 < end; e0 += 16) {
        uint4 v[4];
        bool have[4];
#pragma unroll
        for (int u = 0; u < 4; u++) {
            int e = e0 + u * 4 + g;
            have[u] = (e < end);
            if (have[u]) {
                int s = col[e];
                v[u] = *(const uint4*)(X + (size_t)s * C + seg * 8);
            }
        }
#pragma unroll
        for (int u = 0; u < 4; u++) {
            if (have[u]) {
                const __half2* h = (const __half2*)&v[u];
#pragma unroll
                for (int p = 0; p < 4; p++) {
                    float2 f = __half22float2(h[p]);
                    acc[2 * p] += f.x;
                    acc[2 * p + 1] += f.y;
                }
            }
        }
    }
#pragma unroll
    for (int i = 0; i < 8; i++) {
        acc[i] += __shfl_xor(acc[i], 16);
        acc[i] += __shfl_xor(acc[i], 32);
    }
    int deg = end - beg;
    float inv = 1.0f / (float)((deg > 0) ? deg : 1);
    if (g == 0) {
        __half2 o[4];
#pragma unroll
        for (int p = 0; p < 4; p++)
            o[p] = __floats2half2_rn(acc[2 * p] * inv, acc[2 * p + 1] * inv);
        *(uint4*)(M + (size_t)node * C + seg * 8) = *(uint4*)o;
    }
}

// ---------------- MFMA GEMM: relu(A0@W[:, :128]^T + A1@W[:, 128:]^T + b) --------

template <int HEAD>
__global__ __launch_bounds__(256) void k_gemm_f16(
    const __half* __restrict__ A0, const __half* __restrict__ A1,
    const __half* __restrict__ W, const float* __restrict__ bias,
    __half* __restrict__ Hout, const float* __restrict__ Wo,
    const float* __restrict__ bo, float* __restrict__ out) {
    __shared__ __half As[2][128][40];
    __shared__ __half Bs[2][128][40];
    __shared__ float outs[2][128];

    const int tid = threadIdx.x;
    const int n0 = blockIdx.x * 128;
    const int wid = tid >> 6, lane = tid & 63;
    const int wr = wid >> 1, wc = wid & 1;
    const int l15 = lane & 15, lk = lane >> 4;

    f32x4 acc[4][4];
#pragma unroll
    for (int m = 0; m < 4; m++)
#pragma unroll
        for (int n = 0; n < 4; n++) acc[m][n] = (f32x4)(0.0f);

    const int row0 = tid >> 2, seg0 = (tid & 3) * 8;
    const int row1 = (tid + 256) >> 2, seg1 = seg0;

    uint4 ra[2], rb[2];
    auto stage_load = [&](int t) {
        int kg = t * 32;
        const __half* Ap = (kg < 128) ? A0 : A1;
        int k0 = kg & 127;
        int n_ = n0 + row0;
        ra[0] = (n_ < N_NODES) ? *(const uint4*)(Ap + (size_t)n_ * C + k0 + seg0)
                               : make_uint4(0, 0, 0, 0);
        rb[0] = *(const uint4*)(W + row0 * 256 + kg + seg0);
        n_ = n0 + row1;
        ra[1] = (n_ < N_NODES) ? *(const uint4*)(Ap + (size_t)n_ * C + k0 + seg1)
                               : make_uint4(0, 0, 0, 0);
        rb[1] = *(const uint4*)(W + row1 * 256 + kg + seg1);
    };
    auto stage_write = [&](int b) {
        *(uint4*)&As[b][row0][seg0] = ra[0];
        *(uint4*)&Bs[b][row0][seg0] = rb[0];
        *(uint4*)&As[b][row1][seg1] = ra[1];
        *(uint4*)&Bs[b][row1][seg1] = rb[1];
    };

    stage_load(0);
    stage_write(0);
    __syncthreads();

    for (int t = 0; t < 8; t++) {
        int cur = t & 1;
        if (t < 7) stage_load(t + 1);
        half8 af[4], bf[4];
#pragma unroll
        for (int m = 0; m < 4; m++)
            af[m] = *(const half8*)&As[cur][wr * 64 + m * 16 + l15][lk * 8];
#pragma unroll
        for (int n = 0; n < 4; n++)
            bf[n] = *(const half8*)&Bs[cur][wc * 64 + n * 16 + l15][lk * 8];
#pragma unroll
        for (int m = 0; m < 4; m++)
#pragma unroll
            for (int n = 0; n < 4; n++)
                acc[m][n] =
                    __builtin_amdgcn_mfma_f32_16x16x32_f16(af[m], bf[n], acc[m][n], 0, 0, 0);
        if (t < 7) stage_write(cur ^ 1);
        __syncthreads();
    }

    float bv[4];
#pragma unroll
    for (int n = 0; n < 4; n++) bv[n] = bias[wc * 64 + n * 16 + l15];
#pragma unroll
    for (int m = 0; m < 4; m++)
#pragma unroll
        for (int n = 0; n < 4; n++)
#pragma unroll
            for (int r = 0; r < 4; r++)
                acc[m][n][r] = fmaxf(acc[m][n][r] + bv[n], 0.f);

    if (!HEAD) {
#pragma unroll
        for (int m = 0; m < 4; m++) {
#pragma unroll
            for (int r = 0; r < 4; r++) {
                int n_ = n0 + wr * 64 + m * 16 + lk * 4 + r;
                if (n_ < N_NODES) {
#pragma unroll
                    for (int n = 0; n < 4; n++)
                        Hout[(size_t)n_ * C + wc * 64 + n * 16 + l15] =
                            __float2half_rn(acc[m][n][r]);
                }
            }
        }
    } else {
        float wv[4];
#pragma unroll
        for (int n = 0; n < 4; n++) wv[n] = Wo[wc * 64 + n * 16 + l15];
#pragma unroll
        for (int m = 0; m < 4; m++) {
#pragma unroll
            for (int r = 0; r < 4; r++) {
                float p = acc[m][0][r] * wv[0] + acc[m][1][r] * wv[1] +
                          acc[m][2][r] * wv[2] + acc[m][3][r] * wv[3];
                p += __shfl_xor(p, 1);
                p += __shfl_xor(p, 2);
                p += __shfl_xor(p, 4);
                p += __shfl_xor(p, 8);
                if (l15 == 0) outs[wc][wr * 64 + m * 16 + lk * 4 + r] = p;
            }
        }
        __syncthreads();
        if (tid < 128) {
            int n_ = n0 + tid;
            if (n_ < N_NODES) out[n_] = outs[0][tid] + outs[1][tid] + bo[0];
        }
    }
}

// ---------------- launch ----------------

extern "C" void kernel_launch(void* const* d_in, const int* in_sizes, int n_in,
                              void* d_out, int out_size, void* d_ws, size_t ws_size,
                              hipStream_t stream) {
    const float* x   = (const float*)d_in[0];
    const int*   ei  = (const int*)d_in[1];
    const float* Wl1 = (const float*)d_in[2];
    const float* bl1 = (const float*)d_in[3];
    const float* Wr1 = (const float*)d_in[4];
    const float* Wl2 = (const float*)d_in[5];
    const float* bl2 = (const float*)d_in[6];
    const float* Wr2 = (const float*)d_in[7];
    const float* Wo  = (const float*)d_in[8];
    const float* bo  = (const float*)d_in[9];
    float* out = (float*)d_out;

    const int* src = ei;
    const int* dst = ei + N_EDGES;

    char* ws = (char*)d_ws;
    auto carve = [&](size_t bytes) {
        char* p = ws;
        ws += (bytes + 1023) & ~(size_t)1023;
        return p;
    };
    int*    gb     = (int*)carve((size_t)NBKT * 4);
    int*    gbase  = (int*)carve((size_t)(NBKT + 1) * 4);
    int*    gcur   = (int*)carve((size_t)NBKT * 4);
    int*    rowptr = (int*)carve((size_t)(N_NODES + 1) * 4);
    int*    col    = (int*)carve((size_t)N_EDGES * 4);
    uint2*  S      = (uint2*)carve((size_t)N_EDGES * 8);
    __half* Xh     = (__half*)carve((size_t)N_NODES * C * 2);
    __half* Mh     = (__half*)carve((size_t)N_NODES * C * 2);
    __half* Hh     = (__half*)carve((size_t)N_NODES * C * 2);
    __half* Wc1    = (__half*)carve((size_t)128 * 256 * 2);
    __half* Wc2    = (__half*)carve((size_t)128 * 256 * 2);

    // binned CSR build
    k_zero_int<<<1, 256, 0, stream>>>(gb, NBKT);
    k_bcount<<<STG_BLOCKS, STG_THREADS, 0, stream>>>(dst, gb);
    k_bscan<<<1, 128, 0, stream>>>(gb, gbase, gcur, rowptr);
    k_bstage<<<STG_BLOCKS, STG_THREADS, 0, stream>>>(src, dst, gcur, S);
    k_bfine<<<NBKT, 1024, 0, stream>>>(S, gbase, rowptr, col);

    // fp16 conversions / weight packing
    int n4 = N_NODES * C / 4;
    k_cvt<<<(n4 + 255) / 256, 256, 0, stream>>>(x, Xh, n4);
    k_prepw<<<128, 256, 0, stream>>>(Wl1, Wr1, Wc1);
    k_prepw<<<128, 256, 0, stream>>>(Wl2, Wr2, Wc2);

    dim3 gN((N_NODES + 3) / 4), b256(256);
    dim3 gG((N_NODES + 127) / 128);

    // layer 1
    k_mean_f16<<<gN, b256, 0, stream>>>(Xh, Mh, rowptr, col);
    k_gemm_f16<0><<<gG, b256, 0, stream>>>(Xh, Mh, Wc1, bl1, Hh, nullptr, nullptr, nullptr);
    // layer 2 + fused head
    k_mean_f16<<<gN, b256, 0, stream>>>(Hh, Mh, rowptr, col);
    k_gemm_f16<1><<<gG, b256, 0, stream>>>(Hh, Mh, Wc2, bl2, nullptr, Wo, bo, out);
}

// Round 6
// 251.910 us; speedup vs baseline: 4.4714x; 1.0616x over previous
//
#include <hip/hip_runtime.h>
#include <hip/hip_fp16.h>

#define N_NODES 100000
#define N_EDGES 1600000
#define C 128

// binned CSR build
#define NB_SHIFT 10
#define NB (1 << NB_SHIFT)                        // 1024 nodes per bucket
#define NBKT ((N_NODES + NB - 1) >> NB_SHIFT)     // 98 buckets
#define CPT 4096                                  // edges per stage block
#define STG_THREADS 512
#define STG_BLOCKS ((N_EDGES + CPT - 1) / CPT)    // 391

typedef _Float16 half8 __attribute__((ext_vector_type(8)));
typedef float f32x4 __attribute__((ext_vector_type(4)));

__global__ void k_zero_int(int* __restrict__ p, int n) {
    int i = blockIdx.x * blockDim.x + threadIdx.x;
    if (i < n) p[i] = 0;
}

// ---- pass A: per-bucket edge counts (LDS-aggregated) ----
__global__ __launch_bounds__(512) void k_bcount(const int* __restrict__ dst,
                                                int* __restrict__ gb) {
    __shared__ int hist[128];
    int t = threadIdx.x;
    int base = blockIdx.x * CPT;
    if (t < 128) hist[t] = 0;
    __syncthreads();
#pragma unroll
    for (int i = 0; i < 8; i++) {
        int e = base + i * STG_THREADS + t;
        if (e < N_EDGES) atomicAdd(&hist[dst[e] >> NB_SHIFT], 1);
    }
    __syncthreads();
    if (t < NBKT) {
        int h = hist[t];
        if (h) atomicAdd(&gb[t], h);
    }
}

// ---- pass B: scan bucket counts -> gbase (and init gcur) ----
__global__ __launch_bounds__(128) void k_bscan(const int* __restrict__ gb,
                                               int* __restrict__ gbase,
                                               int* __restrict__ gcur,
                                               int* __restrict__ rowptr) {
    __shared__ int sc[128];
    int t = threadIdx.x;
    int v = (t < NBKT) ? gb[t] : 0;
    sc[t] = v;
    __syncthreads();
    for (int off = 1; off < 128; off <<= 1) {
        int u = (t >= off) ? sc[t - off] : 0;
        __syncthreads();
        sc[t] += u;
        __syncthreads();
    }
    if (t < NBKT) {
        int e = sc[t] - v;  // exclusive
        gbase[t] = e;
        gcur[t] = e;
    }
    if (t == 0) {
        gbase[NBKT] = N_EDGES;
        rowptr[N_NODES] = N_EDGES;
    }
}

// ---- pass C: binned stage -> S[(src,dst)] grouped by bucket ----
__global__ __launch_bounds__(512) void k_bstage(const int* __restrict__ src,
                                                const int* __restrict__ dst,
                                                int* __restrict__ gcur,
                                                uint2* __restrict__ S) {
    __shared__ int hist[128], sc[128], lstart[128], gbaseL[128];
    __shared__ uint2 stg[CPT];
    int t = threadIdx.x;
    int base = blockIdx.x * CPT;
    int cnt = N_EDGES - base;
    if (cnt > CPT) cnt = CPT;
    if (t < 128) hist[t] = 0;
    __syncthreads();
    unsigned s_[8], d_[8];
    int r_[8], b_[8];
#pragma unroll
    for (int i = 0; i < 8; i++) {
        int li = i * STG_THREADS + t;
        if (li < cnt) {
            int e = base + li;
            s_[i] = src[e];
            d_[i] = dst[e];
            b_[i] = d_[i] >> NB_SHIFT;
            r_[i] = atomicAdd(&hist[b_[i]], 1);
        } else {
            r_[i] = -1;
        }
    }
    __syncthreads();
    int hv = (t < 128) ? hist[t] : 0;
    if (t < 128) sc[t] = hv;
    __syncthreads();
    for (int off = 1; off < 128; off <<= 1) {
        int u = (t < 128 && t >= off) ? sc[t - off] : 0;
        __syncthreads();
        if (t < 128) sc[t] += u;
        __syncthreads();
    }
    if (t < 128) lstart[t] = sc[t] - hv;
    if (t < NBKT) gbaseL[t] = hv ? atomicAdd(&gcur[t], hv) : 0;
    __syncthreads();
#pragma unroll
    for (int i = 0; i < 8; i++)
        if (r_[i] >= 0) stg[lstart[b_[i]] + r_[i]] = make_uint2(s_[i], d_[i]);
    __syncthreads();
    for (int slot = t; slot < cnt; slot += STG_THREADS) {
        uint2 ed = stg[slot];
        int b = ed.y >> NB_SHIFT;
        S[gbaseL[b] + (slot - lstart[b])] = ed;
    }
}

// ---- pass D: per-bucket fine counting sort -> rowptr + col ----
__global__ __launch_bounds__(1024) void k_bfine(const uint2* __restrict__ S,
                                                const int* __restrict__ gbase,
                                                int* __restrict__ rowptr,
                                                int* __restrict__ col) {
    __shared__ int hist[NB];
    __shared__ int wsum[16];
    int t = threadIdx.x, b = blockIdx.x;
    int nbeg = b << NB_SHIFT;
    int ebeg = gbase[b], eend = gbase[b + 1];
    hist[t] = 0;
    __syncthreads();
    for (int e = ebeg + t; e < eend; e += 1024) atomicAdd(&hist[S[e].y - nbeg], 1);
    __syncthreads();
    int v = hist[t];
    int inc = v;
    int lane = t & 63, wid = t >> 6;
#pragma unroll
    for (int off = 1; off < 64; off <<= 1) {
        int u = __shfl_up(inc, off);
        if (lane >= off) inc += u;
    }
    if (lane == 63) wsum[wid] = inc;
    __syncthreads();
    if (t < 16) {
        int w = wsum[t];
        int wi = w;
#pragma unroll
        for (int off = 1; off < 16; off <<= 1) {
            int u = __shfl_up(wi, off);
            if (t >= off) wi += u;
        }
        wsum[t] = wi;  // inclusive wave sums
    }
    __syncthreads();
    int woff = (wid == 0) ? 0 : wsum[wid - 1];
    int excl = inc - v + woff;
    int g = nbeg + t;
    if (g < N_NODES) rowptr[g] = ebeg + excl;
    __syncthreads();
    hist[t] = excl;  // becomes fill cursor (local offset within bucket)
    __syncthreads();
    for (int e = ebeg + t; e < eend; e += 1024) {
        uint2 ed = S[e];
        int p = atomicAdd(&hist[ed.y - nbeg], 1);
        col[ebeg + p] = ed.x;
    }
}

// ---------------- fp32 -> fp16 feature convert ----------------

__global__ void k_cvt(const float* __restrict__ X, __half* __restrict__ Y, int n4) {
    int i = blockIdx.x * blockDim.x + threadIdx.x;
    if (i < n4) {
        float4 v = ((const float4*)X)[i];
        __half2 a = __floats2half2_rn(v.x, v.y);
        __half2 b = __floats2half2_rn(v.z, v.w);
        ((__half2*)Y)[i * 2] = a;
        ((__half2*)Y)[i * 2 + 1] = b;
    }
}

__global__ void k_prepw(const float* __restrict__ Wl, const float* __restrict__ Wr,
                        __half* __restrict__ Wc) {
    int i = blockIdx.x * blockDim.x + threadIdx.x;
    if (i < 128 * 256) {
        int n_ = i >> 8, k = i & 255;
        float v = (k < 128) ? Wl[n_ * 128 + k] : Wr[n_ * 128 + (k - 128)];
        Wc[i] = __float2half_rn(v);
    }
}

// ---------------- mean aggregation: one 16-lane group per node ----------------
// 16 lanes x uint4 = one 256B row. 4 nodes per wave, 16 per block: ~128 node
// chains in flight per CU (vs 22 before). 8-deep unrolled edge chunks keep 8
// gathers outstanding per group; tail handled by clamped masked loads (no
// serial tail chain). Each lane owns its 8 channels -> no cross-lane reduce.

__global__ __launch_bounds__(256) void k_mean_f16(const __half* __restrict__ X,
                                                  __half* __restrict__ M,
                                                  const int* __restrict__ rowptr,
                                                  const int* __restrict__ col) {
    int node = blockIdx.x * 16 + (threadIdx.x >> 4);
    if (node >= N_NODES) return;
    int seg = threadIdx.x & 15;  // 16B segment within 256B row
    int beg = rowptr[node], end = rowptr[node + 1];
    float acc[8];
#pragma unroll
    for (int i = 0; i < 8; i++) acc[i] = 0.f;
    for (int e = beg; e < end; e += 8) {
        uint4 v[8];
        bool val[8];
#pragma unroll
        for (int u = 0; u < 8; u++) {
            int ee = e + u;
            val[u] = (ee < end);
            int s = col[val[u] ? ee : (end - 1)];
            v[u] = *(const uint4*)(X + (size_t)s * C + seg * 8);
        }
#pragma unroll
        for (int u = 0; u < 8; u++) {
            if (val[u]) {
                const __half2* h = (const __half2*)&v[u];
#pragma unroll
                for (int p = 0; p < 4; p++) {
                    float2 f = __half22float2(h[p]);
                    acc[2 * p] += f.x;
                    acc[2 * p + 1] += f.y;
                }
            }
        }
    }
    int deg = end - beg;
    float inv = 1.0f / (float)((deg > 0) ? deg : 1);
    __half2 o[4];
#pragma unroll
    for (int p = 0; p < 4; p++)
        o[p] = __floats2half2_rn(acc[2 * p] * inv, acc[2 * p + 1] * inv);
    *(uint4*)(M + (size_t)node * C + seg * 8) = *(uint4*)o;
}

// ---------------- MFMA GEMM: relu(A0@W[:, :128]^T + A1@W[:, 128:]^T + b) --------

template <int HEAD>
__global__ __launch_bounds__(256) void k_gemm_f16(
    const __half* __restrict__ A0, const __half* __restrict__ A1,
    const __half* __restrict__ W, const float* __restrict__ bias,
    __half* __restrict__ Hout, const float* __restrict__ Wo,
    const float* __restrict__ bo, float* __restrict__ out) {
    __shared__ __half As[2][128][40];
    __shared__ __half Bs[2][128][40];
    __shared__ float outs[2][128];

    const int tid = threadIdx.x;
    const int n0 = blockIdx.x * 128;
    const int wid = tid >> 6, lane = tid & 63;
    const int wr = wid >> 1, wc = wid & 1;
    const int l15 = lane & 15, lk = lane >> 4;

    f32x4 acc[4][4];
#pragma unroll
    for (int m = 0; m < 4; m++)
#pragma unroll
        for (int n = 0; n < 4; n++) acc[m][n] = (f32x4)(0.0f);

    const int row0 = tid >> 2, seg0 = (tid & 3) * 8;
    const int row1 = (tid + 256) >> 2, seg1 = seg0;

    uint4 ra[2], rb[2];
    auto stage_load = [&](int t) {
        int kg = t * 32;
        const __half* Ap = (kg < 128) ? A0 : A1;
        int k0 = kg & 127;
        int n_ = n0 + row0;
        ra[0] = (n_ < N_NODES) ? *(const uint4*)(Ap + (size_t)n_ * C + k0 + seg0)
                               : make_uint4(0, 0, 0, 0);
        rb[0] = *(const uint4*)(W + row0 * 256 + kg + seg0);
        n_ = n0 + row1;
        ra[1] = (n_ < N_NODES) ? *(const uint4*)(Ap + (size_t)n_ * C + k0 + seg1)
                               : make_uint4(0, 0, 0, 0);
        rb[1] = *(const uint4*)(W + row1 * 256 + kg + seg1);
    };
    auto stage_write = [&](int b) {
        *(uint4*)&As[b][row0][seg0] = ra[0];
        *(uint4*)&Bs[b][row0][seg0] = rb[0];
        *(uint4*)&As[b][row1][seg1] = ra[1];
        *(uint4*)&Bs[b][row1][seg1] = rb[1];
    };

    stage_load(0);
    stage_write(0);
    __syncthreads();

    for (int t = 0; t < 8; t++) {
        int cur = t & 1;
        if (t < 7) stage_load(t + 1);
        half8 af[4], bf[4];
#pragma unroll
        for (int m = 0; m < 4; m++)
            af[m] = *(const half8*)&As[cur][wr * 64 + m * 16 + l15][lk * 8];
#pragma unroll
        for (int n = 0; n < 4; n++)
            bf[n] = *(const half8*)&Bs[cur][wc * 64 + n * 16 + l15][lk * 8];
#pragma unroll
        for (int m = 0; m < 4; m++)
#pragma unroll
            for (int n = 0; n < 4; n++)
                acc[m][n] =
                    __builtin_amdgcn_mfma_f32_16x16x32_f16(af[m], bf[n], acc[m][n], 0, 0, 0);
        if (t < 7) stage_write(cur ^ 1);
        __syncthreads();
    }

    float bv[4];
#pragma unroll
    for (int n = 0; n < 4; n++) bv[n] = bias[wc * 64 + n * 16 + l15];
#pragma unroll
    for (int m = 0; m < 4; m++)
#pragma unroll
        for (int n = 0; n < 4; n++)
#pragma unroll
            for (int r = 0; r < 4; r++)
                acc[m][n][r] = fmaxf(acc[m][n][r] + bv[n], 0.f);

    if (!HEAD) {
#pragma unroll
        for (int m = 0; m < 4; m++) {
#pragma unroll
            for (int r = 0; r < 4; r++) {
                int n_ = n0 + wr * 64 + m * 16 + lk * 4 + r;
                if (n_ < N_NODES) {
#pragma unroll
                    for (int n = 0; n < 4; n++)
                        Hout[(size_t)n_ * C + wc * 64 + n * 16 + l15] =
                            __float2half_rn(acc[m][n][r]);
                }
            }
        }
    } else {
        float wv[4];
#pragma unroll
        for (int n = 0; n < 4; n++) wv[n] = Wo[wc * 64 + n * 16 + l15];
#pragma unroll
        for (int m = 0; m < 4; m++) {
#pragma unroll
            for (int r = 0; r < 4; r++) {
                float p = acc[m][0][r] * wv[0] + acc[m][1][r] * wv[1] +
                          acc[m][2][r] * wv[2] + acc[m][3][r] * wv[3];
                p += __shfl_xor(p, 1);
                p += __shfl_xor(p, 2);
                p += __shfl_xor(p, 4);
                p += __shfl_xor(p, 8);
                if (l15 == 0) outs[wc][wr * 64 + m * 16 + lk * 4 + r] = p;
            }
        }
        __syncthreads();
        if (tid < 128) {
            int n_ = n0 + tid;
            if (n_ < N_NODES) out[n_] = outs[0][tid] + outs[1][tid] + bo[0];
        }
    }
}

// ---------------- launch ----------------

extern "C" void kernel_launch(void* const* d_in, const int* in_sizes, int n_in,
                              void* d_out, int out_size, void* d_ws, size_t ws_size,
                              hipStream_t stream) {
    const float* x   = (const float*)d_in[0];
    const int*   ei  = (const int*)d_in[1];
    const float* Wl1 = (const float*)d_in[2];
    const float* bl1 = (const float*)d_in[3];
    const float* Wr1 = (const float*)d_in[4];
    const float* Wl2 = (const float*)d_in[5];
    const float* bl2 = (const float*)d_in[6];
    const float* Wr2 = (const float*)d_in[7];
    const float* Wo  = (const float*)d_in[8];
    const float* bo  = (const float*)d_in[9];
    float* out = (float*)d_out;

    const int* src = ei;
    const int* dst = ei + N_EDGES;

    char* ws = (char*)d_ws;
    auto carve = [&](size_t bytes) {
        char* p = ws;
        ws += (bytes + 1023) & ~(size_t)1023;
        return p;
    };
    int*    gb     = (int*)carve((size_t)NBKT * 4);
    int*    gbase  = (int*)carve((size_t)(NBKT + 1) * 4);
    int*    gcur   = (int*)carve((size_t)NBKT * 4);
    int*    rowptr = (int*)carve((size_t)(N_NODES + 1) * 4);
    int*    col    = (int*)carve((size_t)N_EDGES * 4);
    uint2*  S      = (uint2*)carve((size_t)N_EDGES * 8);
    __half* Xh     = (__half*)carve((size_t)N_NODES * C * 2);
    __half* Mh     = (__half*)carve((size_t)N_NODES * C * 2);
    __half* Hh     = (__half*)carve((size_t)N_NODES * C * 2);
    __half* Wc1    = (__half*)carve((size_t)128 * 256 * 2);
    __half* Wc2    = (__half*)carve((size_t)128 * 256 * 2);

    // binned CSR build
    k_zero_int<<<1, 256, 0, stream>>>(gb, NBKT);
    k_bcount<<<STG_BLOCKS, STG_THREADS, 0, stream>>>(dst, gb);
    k_bscan<<<1, 128, 0, stream>>>(gb, gbase, gcur, rowptr);
    k_bstage<<<STG_BLOCKS, STG_THREADS, 0, stream>>>(src, dst, gcur, S);
    k_bfine<<<NBKT, 1024, 0, stream>>>(S, gbase, rowptr, col);

    // fp16 conversions / weight packing
    int n4 = N_NODES * C / 4;
    k_cvt<<<(n4 + 255) / 256, 256, 0, stream>>>(x, Xh, n4);
    k_prepw<<<128, 256, 0, stream>>>(Wl1, Wr1, Wc1);
    k_prepw<<<128, 256, 0, stream>>>(Wl2, Wr2, Wc2);

    dim3 gN((N_NODES + 15) / 16), b256(256);
    dim3 gG((N_NODES + 127) / 128);

    // layer 1
    k_mean_f16<<<gN, b256, 0, stream>>>(Xh, Mh, rowptr, col);
    k_gemm_f16<0><<<gG, b256, 0, stream>>>(Xh, Mh, Wc1, bl1, Hh, nullptr, nullptr, nullptr);
    // layer 2 + fused head
    k_mean_f16<<<gN, b256, 0, stream>>>(Hh, Mh, rowptr, col);
    k_gemm_f16<1><<<gG, b256, 0, stream>>>(Hh, Mh, Wc2, bl2, nullptr, Wo, bo, out);
}

// Round 7
// 237.646 us; speedup vs baseline: 4.7397x; 1.0600x over previous
//
#include <hip/hip_runtime.h>
#include <hip/hip_fp16.h>

#define N_NODES 100000
#define N_EDGES 1600000
#define C 128

// binned CSR build (fixed-capacity buckets)
#define NB_SHIFT 10
#define NB (1 << NB_SHIFT)                        // 1024 nodes per bucket
#define NBKT ((N_NODES + NB - 1) >> NB_SHIFT)     // 98 buckets
#define CAP 20480                                 // edges per bucket window (avg 16327)
#define CPT 4096                                  // edges per stage block
#define STG_BLOCKS ((N_EDGES + CPT - 1) / CPT)    // 391
#define CVB 782                                   // cvt blocks (512 thr * 8 float4)
#define PWB 32                                    // prepw blocks

typedef _Float16 half8 __attribute__((ext_vector_type(8)));
typedef float f32x4 __attribute__((ext_vector_type(4)));

// ---------------- fused pre-pass: cvt | prepw | binned stage ----------------
// blocks [0,CVB): x fp32 -> Xh fp16
// blocks [CVB,CVB+PWB): pack [Wl|Wr] -> Wc fp16 (both layers)
// blocks [CVB+PWB, +STG_BLOCKS): bucket edges into fixed-capacity S windows

__global__ __launch_bounds__(512) void k_fusedA(
    const float* __restrict__ x, const int* __restrict__ src,
    const int* __restrict__ dst, const float* __restrict__ Wl1,
    const float* __restrict__ Wr1, const float* __restrict__ Wl2,
    const float* __restrict__ Wr2, int* __restrict__ gcur,
    uint2* __restrict__ S, __half* __restrict__ Xh, __half* __restrict__ Wc1,
    __half* __restrict__ Wc2) {
    __shared__ int hist[128], sc[128], lstart[128], gbaseL[128];
    __shared__ uint2 stg[CPT];
    const int bid = blockIdx.x;
    const int t = threadIdx.x;

    if (bid < CVB) {
        // ---- fp32 -> fp16 feature convert ----
        const float4* xin = (const float4*)x;
        __half2* yout = (__half2*)Xh;
#pragma unroll
        for (int i = 0; i < 8; i++) {
            int idx = bid * 4096 + i * 512 + t;
            if (idx < N_NODES * C / 4) {
                float4 v = xin[idx];
                yout[idx * 2] = __floats2half2_rn(v.x, v.y);
                yout[idx * 2 + 1] = __floats2half2_rn(v.z, v.w);
            }
        }
        return;
    }
    if (bid < CVB + PWB) {
        // ---- weight packing (both layers) ----
        int i0 = ((bid - CVB) * 512 + t) * 4;
#pragma unroll
        for (int m = 0; m < 4; m++) {
            int i = i0 + m;
            if (i < 2 * 128 * 256) {
                int set = i >> 15;       // 0: layer1, 1: layer2
                int j = i & 32767;
                int n_ = j >> 8, k = j & 255;
                const float* Wl = set ? Wl2 : Wl1;
                const float* Wr = set ? Wr2 : Wr1;
                float v = (k < 128) ? Wl[n_ * 128 + k] : Wr[n_ * 128 + (k - 128)];
                (set ? Wc2 : Wc1)[j] = __float2half_rn(v);
            }
        }
        return;
    }

    // ---- binned stage ----
    int base = (bid - CVB - PWB) * CPT;
    int cnt = N_EDGES - base;
    if (cnt > CPT) cnt = CPT;
    if (t < 128) hist[t] = 0;
    __syncthreads();
    unsigned s_[8], d_[8];
    int r_[8], b_[8];
#pragma unroll
    for (int i = 0; i < 8; i++) {
        int li = i * 512 + t;
        if (li < cnt) {
            int e = base + li;
            s_[i] = src[e];
            d_[i] = dst[e];
            b_[i] = d_[i] >> NB_SHIFT;
            r_[i] = atomicAdd(&hist[b_[i]], 1);
        } else {
            r_[i] = -1;
        }
    }
    __syncthreads();
    int hv = (t < 128) ? hist[t] : 0;
    if (t < 128) sc[t] = hv;
    __syncthreads();
    for (int off = 1; off < 128; off <<= 1) {
        int u = (t < 128 && t >= off) ? sc[t - off] : 0;
        __syncthreads();
        if (t < 128) sc[t] += u;
        __syncthreads();
    }
    if (t < 128) lstart[t] = sc[t] - hv;
    if (t < NBKT && hv) gbaseL[t] = t * CAP + atomicAdd(&gcur[t], hv);
    __syncthreads();
#pragma unroll
    for (int i = 0; i < 8; i++)
        if (r_[i] >= 0) stg[lstart[b_[i]] + r_[i]] = make_uint2(s_[i], d_[i]);
    __syncthreads();
    for (int slot = t; slot < cnt; slot += 512) {
        uint2 ed = stg[slot];
        int b = ed.y >> NB_SHIFT;
        S[gbaseL[b] + (slot - lstart[b])] = ed;
    }
}

// ---- per-bucket fine counting sort -> rowbeg/rowend + col (gapped windows) ----
__global__ __launch_bounds__(1024) void k_bfine(const uint2* __restrict__ S,
                                                const int* __restrict__ gcur,
                                                int* __restrict__ rowbeg,
                                                int* __restrict__ rowend,
                                                int* __restrict__ col) {
    __shared__ int hist[NB];
    __shared__ int wsum[16];
    int t = threadIdx.x, b = blockIdx.x;
    int nbeg = b << NB_SHIFT;
    int ebeg = b * CAP;
    int cnt = gcur[b];
    hist[t] = 0;
    __syncthreads();
    for (int e = t; e < cnt; e += 1024) atomicAdd(&hist[S[ebeg + e].y - nbeg], 1);
    __syncthreads();
    int v = hist[t];
    int inc = v;
    int lane = t & 63, wid = t >> 6;
#pragma unroll
    for (int off = 1; off < 64; off <<= 1) {
        int u = __shfl_up(inc, off);
        if (lane >= off) inc += u;
    }
    if (lane == 63) wsum[wid] = inc;
    __syncthreads();
    if (t < 16) {
        int wi = wsum[t];
#pragma unroll
        for (int off = 1; off < 16; off <<= 1) {
            int u = __shfl_up(wi, off);
            if (t >= off) wi += u;
        }
        wsum[t] = wi;  // inclusive wave sums
    }
    __syncthreads();
    int woff = (wid == 0) ? 0 : wsum[wid - 1];
    int excl = inc - v + woff;
    int g = nbeg + t;
    if (g < N_NODES) {
        rowbeg[g] = ebeg + excl;
        rowend[g] = ebeg + excl + v;
    }
    __syncthreads();
    hist[t] = excl;  // fill cursor (local offset within bucket)
    __syncthreads();
    for (int e = t; e < cnt; e += 1024) {
        uint2 ed = S[ebeg + e];
        int p = atomicAdd(&hist[ed.y - nbeg], 1);
        col[ebeg + p] = ed.x;
    }
}

// ---------------- mean aggregation: one 16-lane group per node ----------------

__global__ __launch_bounds__(256) void k_mean_f16(const __half* __restrict__ X,
                                                  __half* __restrict__ M,
                                                  const int* __restrict__ rowbeg,
                                                  const int* __restrict__ rowend,
                                                  const int* __restrict__ col) {
    int node = blockIdx.x * 16 + (threadIdx.x >> 4);
    if (node >= N_NODES) return;
    int seg = threadIdx.x & 15;  // 16B segment within 256B row
    int beg = rowbeg[node], end = rowend[node];
    float acc[8];
#pragma unroll
    for (int i = 0; i < 8; i++) acc[i] = 0.f;
    for (int e = beg; e < end; e += 8) {
        uint4 v[8];
        bool val[8];
#pragma unroll
        for (int u = 0; u < 8; u++) {
            int ee = e + u;
            val[u] = (ee < end);
            int s = col[val[u] ? ee : (end - 1)];
            v[u] = *(const uint4*)(X + (size_t)s * C + seg * 8);
        }
#pragma unroll
        for (int u = 0; u < 8; u++) {
            if (val[u]) {
                const __half2* h = (const __half2*)&v[u];
#pragma unroll
                for (int p = 0; p < 4; p++) {
                    float2 f = __half22float2(h[p]);
                    acc[2 * p] += f.x;
                    acc[2 * p + 1] += f.y;
                }
            }
        }
    }
    int deg = end - beg;
    float inv = 1.0f / (float)((deg > 0) ? deg : 1);
    __half2 o[4];
#pragma unroll
    for (int p = 0; p < 4; p++)
        o[p] = __floats2half2_rn(acc[2 * p] * inv, acc[2 * p + 1] * inv);
    *(uint4*)(M + (size_t)node * C + seg * 8) = *(uint4*)o;
}

// ---------------- MFMA GEMM: relu(A0@W[:, :128]^T + A1@W[:, 128:]^T + b) --------

template <int HEAD>
__global__ __launch_bounds__(256) void k_gemm_f16(
    const __half* __restrict__ A0, const __half* __restrict__ A1,
    const __half* __restrict__ W, const float* __restrict__ bias,
    __half* __restrict__ Hout, const float* __restrict__ Wo,
    const float* __restrict__ bo, float* __restrict__ out) {
    __shared__ __half As[2][128][40];
    __shared__ __half Bs[2][128][40];
    __shared__ float outs[2][128];

    const int tid = threadIdx.x;
    const int n0 = blockIdx.x * 128;
    const int wid = tid >> 6, lane = tid & 63;
    const int wr = wid >> 1, wc = wid & 1;
    const int l15 = lane & 15, lk = lane >> 4;

    f32x4 acc[4][4];
#pragma unroll
    for (int m = 0; m < 4; m++)
#pragma unroll
        for (int n = 0; n < 4; n++) acc[m][n] = (f32x4)(0.0f);

    const int row0 = tid >> 2, seg0 = (tid & 3) * 8;
    const int row1 = (tid + 256) >> 2, seg1 = seg0;

    uint4 ra[2], rb[2];
    auto stage_load = [&](int t) {
        int kg = t * 32;
        const __half* Ap = (kg < 128) ? A0 : A1;
        int k0 = kg & 127;
        int n_ = n0 + row0;
        ra[0] = (n_ < N_NODES) ? *(const uint4*)(Ap + (size_t)n_ * C + k0 + seg0)
                               : make_uint4(0, 0, 0, 0);
        rb[0] = *(const uint4*)(W + row0 * 256 + kg + seg0);
        n_ = n0 + row1;
        ra[1] = (n_ < N_NODES) ? *(const uint4*)(Ap + (size_t)n_ * C + k0 + seg1)
                               : make_uint4(0, 0, 0, 0);
        rb[1] = *(const uint4*)(W + row1 * 256 + kg + seg1);
    };
    auto stage_write = [&](int b) {
        *(uint4*)&As[b][row0][seg0] = ra[0];
        *(uint4*)&Bs[b][row0][seg0] = rb[0];
        *(uint4*)&As[b][row1][seg1] = ra[1];
        *(uint4*)&Bs[b][row1][seg1] = rb[1];
    };

    stage_load(0);
    stage_write(0);
    __syncthreads();

    for (int t = 0; t < 8; t++) {
        int cur = t & 1;
        if (t < 7) stage_load(t + 1);
        half8 af[4], bf[4];
#pragma unroll
        for (int m = 0; m < 4; m++)
            af[m] = *(const half8*)&As[cur][wr * 64 + m * 16 + l15][lk * 8];
#pragma unroll
        for (int n = 0; n < 4; n++)
            bf[n] = *(const half8*)&Bs[cur][wc * 64 + n * 16 + l15][lk * 8];
#pragma unroll
        for (int m = 0; m < 4; m++)
#pragma unroll
            for (int n = 0; n < 4; n++)
                acc[m][n] =
                    __builtin_amdgcn_mfma_f32_16x16x32_f16(af[m], bf[n], acc[m][n], 0, 0, 0);
        if (t < 7) stage_write(cur ^ 1);
        __syncthreads();
    }

    float bv[4];
#pragma unroll
    for (int n = 0; n < 4; n++) bv[n] = bias[wc * 64 + n * 16 + l15];
#pragma unroll
    for (int m = 0; m < 4; m++)
#pragma unroll
        for (int n = 0; n < 4; n++)
#pragma unroll
            for (int r = 0; r < 4; r++)
                acc[m][n][r] = fmaxf(acc[m][n][r] + bv[n], 0.f);

    if (!HEAD) {
#pragma unroll
        for (int m = 0; m < 4; m++) {
#pragma unroll
            for (int r = 0; r < 4; r++) {
                int n_ = n0 + wr * 64 + m * 16 + lk * 4 + r;
                if (n_ < N_NODES) {
#pragma unroll
                    for (int n = 0; n < 4; n++)
                        Hout[(size_t)n_ * C + wc * 64 + n * 16 + l15] =
                            __float2half_rn(acc[m][n][r]);
                }
            }
        }
    } else {
        float wv[4];
#pragma unroll
        for (int n = 0; n < 4; n++) wv[n] = Wo[wc * 64 + n * 16 + l15];
#pragma unroll
        for (int m = 0; m < 4; m++) {
#pragma unroll
            for (int r = 0; r < 4; r++) {
                float p = acc[m][0][r] * wv[0] + acc[m][1][r] * wv[1] +
                          acc[m][2][r] * wv[2] + acc[m][3][r] * wv[3];
                p += __shfl_xor(p, 1);
                p += __shfl_xor(p, 2);
                p += __shfl_xor(p, 4);
                p += __shfl_xor(p, 8);
                if (l15 == 0) outs[wc][wr * 64 + m * 16 + lk * 4 + r] = p;
            }
        }
        __syncthreads();
        if (tid < 128) {
            int n_ = n0 + tid;
            if (n_ < N_NODES) out[n_] = outs[0][tid] + outs[1][tid] + bo[0];
        }
    }
}

// ---------------- launch ----------------

extern "C" void kernel_launch(void* const* d_in, const int* in_sizes, int n_in,
                              void* d_out, int out_size, void* d_ws, size_t ws_size,
                              hipStream_t stream) {
    const float* x   = (const float*)d_in[0];
    const int*   ei  = (const int*)d_in[1];
    const float* Wl1 = (const float*)d_in[2];
    const float* bl1 = (const float*)d_in[3];
    const float* Wr1 = (const float*)d_in[4];
    const float* Wl2 = (const float*)d_in[5];
    const float* bl2 = (const float*)d_in[6];
    const float* Wr2 = (const float*)d_in[7];
    const float* Wo  = (const float*)d_in[8];
    const float* bo  = (const float*)d_in[9];
    float* out = (float*)d_out;

    const int* src = ei;
    const int* dst = ei + N_EDGES;

    char* ws = (char*)d_ws;
    auto carve = [&](size_t bytes) {
        char* p = ws;
        ws += (bytes + 1023) & ~(size_t)1023;
        return p;
    };
    int*    gcur   = (int*)carve((size_t)NBKT * 4);
    int*    rowbeg = (int*)carve((size_t)N_NODES * 4);
    int*    rowend = (int*)carve((size_t)N_NODES * 4);
    int*    col    = (int*)carve((size_t)NBKT * CAP * 4);
    uint2*  S      = (uint2*)carve((size_t)NBKT * CAP * 8);
    __half* Xh     = (__half*)carve((size_t)N_NODES * C * 2);
    __half* Mh     = (__half*)carve((size_t)N_NODES * C * 2);
    __half* Hh     = (__half*)carve((size_t)N_NODES * C * 2);
    __half* Wc1    = (__half*)carve((size_t)128 * 256 * 2);
    __half* Wc2    = (__half*)carve((size_t)128 * 256 * 2);

    hipMemsetAsync(gcur, 0, (size_t)NBKT * 4, stream);

    // fused cvt + weight-pack + binned stage
    k_fusedA<<<CVB + PWB + STG_BLOCKS, 512, 0, stream>>>(
        x, src, dst, Wl1, Wr1, Wl2, Wr2, gcur, S, Xh, Wc1, Wc2);
    // per-bucket counting sort -> rowbeg/rowend + col
    k_bfine<<<NBKT, 1024, 0, stream>>>(S, gcur, rowbeg, rowend, col);

    dim3 gN((N_NODES + 15) / 16), b256(256);
    dim3 gG((N_NODES + 127) / 128);

    // layer 1
    k_mean_f16<<<gN, b256, 0, stream>>>(Xh, Mh, rowbeg, rowend, col);
    k_gemm_f16<0><<<gG, b256, 0, stream>>>(Xh, Mh, Wc1, bl1, Hh, nullptr, nullptr, nullptr);
    // layer 2 + fused head
    k_mean_f16<<<gN, b256, 0, stream>>>(Hh, Mh, rowbeg, rowend, col);
    k_gemm_f16<1><<<gG, b256, 0, stream>>>(Hh, Mh, Wc2, bl2, nullptr, Wo, bo, out);
}